// Round 4
// baseline (1653.488 us; speedup 1.0000x reference)
//
#include <hip/hip_runtime.h>
#include <hip/hip_cooperative_groups.h>

namespace cg = cooperative_groups;

// Problem constants
#define D    128      // d+1
#define DM   127      // d
#define NP1  1024     // N+1
#define B    8
#define H    8
#define NL   4

// Workspace layout (float offsets)
#define WS_QF 0                         // [NL][H][128][128] padded Q * (1/N)
#define WS_PT (WS_QF + NL*H*D*D)        // [NL][H][128][128] padded+transposed P
#define WS_G  (WS_PT + NL*H*D*D)        // [B][128][128] reduced Gram
#define WS_GS (WS_G  + B*D*D)           // [B][8][128][128] shared: Gp partials, then Sp partials
#define WS_S  (WS_GS + B*8*D*D)         // [B][128][128] S = sum_h Sp

// Async global->LDS, 16B/lane. LDS dest = wave-uniform base + lane*16.
__device__ __forceinline__ void async16(const float* g, float* l)
{
    __builtin_amdgcn_global_load_lds(
        (const __attribute__((address_space(1))) void*)g,
        (__attribute__((address_space(3))) void*)l,
        16, 0, 0);
}

#define VMDRAIN asm volatile("s_waitcnt vmcnt(0)" ::: "memory")

// ===========================================================================
// PATH A: single persistent cooperative kernel. 256 blocks x 256 threads,
// 1 block/CU. Every phase self-contained (round-1-proven staging + sync);
// grid syncs (+ threadfence) order global producer->consumer edges.
// LDS: A_ 64KB | B_ 64KB | C_ 16.5KB  (144.5 KB)
// ===========================================================================
__global__ __launch_bounds__(256) void fused_all(
    const float* __restrict__ Z0, const float* __restrict__ ap,
    float* __restrict__ Qf, float* __restrict__ Pt,
    float* __restrict__ G, float* __restrict__ GS,
    float* __restrict__ S, float* __restrict__ out)
{
    cg::grid_group grid = cg::this_grid();
    const int bid = blockIdx.x;
    const int t   = threadIdx.x;

    __shared__ float A_[16384];   // 64 KB
    __shared__ float B_[16384];   // 64 KB
    __shared__ float C_[4224];    // 16.5 KB

    // ---- prep (once): pad/transpose all layers' params; 1/N folded into Qf ----
    {
        const float inv = 1.0f / 1023.0f;
        const int base = bid * 4096 + t * 16;
        #pragma unroll
        for (int e = 0; e < 16; ++e) {
            const int idx   = base + e;
            const int l     = idx >> 18;
            const int loc18 = idx & 262143;
            const int isP   = loc18 >> 17;
            const int local = loc18 & 131071;
            const int h = local >> 14;
            const int r = (local >> 7) & 127;
            const int c = local & 127;
            const float* apl = ap + (size_t)l * H * 2 * DM * DM;
            if (!isP) {
                float v = (r < DM && c < DM) ? apl[(h*2 + 1)*DM*DM + r*DM + c] * inv : 0.f;
                Qf[(size_t)l * H * D * D + local] = v;
            } else {
                float v;
                if (r < DM && c < DM)        v = apl[(h*2 + 0)*DM*DM + c*DM + r];
                else if (r == DM && c == DM) v = 1.f;
                else                         v = 0.f;
                Pt[(size_t)l * H * D * D + local] = v;
            }
        }
    }
    // First consumer of Qf/Pt is the ts phase, two grid syncs away -> ordered.

    const float* Zcur = Z0;
    for (int l = 0; l < NL; ++l) {
        //================ gp: partial Grams ================
        {
            const int c = bid & 7, q = (bid >> 3) & 3, b = bid >> 5;
            const float* src = Zcur + ((size_t)b * NP1 + c * 128) * D;
            VMDRAIN;
            #pragma unroll
            for (int i = 0; i < 16; ++i)
                async16(src + (t + 256 * i) * 4, A_ + (t + 256 * i) * 4);
            VMDRAIN;
            __syncthreads();
            if (c == 7) {   // key mask: zero token 1023 (row 127); c uniform/block
                if (t < 32) ((float4*)A_)[4064 + t] = make_float4(0.f, 0.f, 0.f, 0.f);
                __syncthreads();
            }

            const int ty = t >> 3, tx = t & 7;
            const int i0 = ty * 4, j0 = q * 32 + tx * 4;
            float acc[4][4] = {};
            #pragma unroll 4
            for (int k = 0; k < 128; ++k) {
                const float4 a  = *(const float4*)&A_[k * 128 + i0];
                const float4 cc = *(const float4*)&A_[k * 128 + j0];
                acc[0][0] += a.x*cc.x; acc[0][1] += a.x*cc.y; acc[0][2] += a.x*cc.z; acc[0][3] += a.x*cc.w;
                acc[1][0] += a.y*cc.x; acc[1][1] += a.y*cc.y; acc[1][2] += a.y*cc.z; acc[1][3] += a.y*cc.w;
                acc[2][0] += a.z*cc.x; acc[2][1] += a.z*cc.y; acc[2][2] += a.z*cc.z; acc[2][3] += a.z*cc.w;
                acc[3][0] += a.w*cc.x; acc[3][1] += a.w*cc.y; acc[3][2] += a.w*cc.z; acc[3][3] += a.w*cc.w;
            }

            float* Gb = GS + ((size_t)(b * 8 + c)) * D * D;
            #pragma unroll
            for (int r = 0; r < 4; ++r)
                *(float4*)&Gb[(i0 + r) * D + j0] =
                    make_float4(acc[r][0], acc[r][1], acc[r][2], acc[r][3]);
        }
        __threadfence(); grid.sync(); __threadfence();   // S1

        //================ gred: G[b] = sum_c Gp[b][c] ================
        if (bid < 128) {
            const int sx = bid & 15, b = bid >> 4;
            const int idx4 = sx * 256 + t;
            float4 sum = make_float4(0.f, 0.f, 0.f, 0.f);
            #pragma unroll
            for (int c = 0; c < 8; ++c) {
                const float4 v = ((const float4*)GS)[(size_t)(b * 8 + c) * 4096 + idx4];
                sum.x += v.x; sum.y += v.y; sum.z += v.z; sum.w += v.w;
            }
            ((float4*)G)[(size_t)b * 4096 + idx4] = sum;
        }
        __threadfence(); grid.sync(); __threadfence();   // S2

        //================ ts: Sp = (Q @ G) @ Pt ================
        {
            const int s = bid & 3, h = (bid >> 2) & 7, b = bid >> 5;
            const int ty = t >> 4, tx = t & 15;
            const int j0 = 4 * tx, j1 = 64 + 4 * tx;

            VMDRAIN;
            const float* qsrc = Qf + (size_t)l * H * D * D + ((size_t)h * D + s * 32) * D;
            #pragma unroll
            for (int i = 0; i < 4; ++i)  async16(qsrc + (t + 256 * i) * 4, C_ + (t + 256 * i) * 4);
            const float* gsrc = G + (size_t)b * D * D;
            #pragma unroll
            for (int i = 0; i < 16; ++i) async16(gsrc + (t + 256 * i) * 4, A_ + (t + 256 * i) * 4);
            const float* psrc = Pt + (size_t)l * H * D * D + (size_t)h * D * D;
            #pragma unroll
            for (int i = 0; i < 16; ++i) async16(psrc + (t + 256 * i) * 4, B_ + (t + 256 * i) * 4);

            // wait for Q+G only (16 Pt loads still in flight), then barrier
            asm volatile("s_waitcnt vmcnt(16)" ::: "memory");
            __builtin_amdgcn_s_barrier();
            asm volatile("" ::: "memory");

            // ---- phase 1: T(32x128) = Q @ G ----
            float acc[2][8] = {};
            #pragma unroll 2
            for (int k4 = 0; k4 < 32; ++k4) {
                const float4 q0 = *(const float4*)&C_[ty * 128 + k4 * 4];
                const float4 q1 = *(const float4*)&C_[(ty + 16) * 128 + k4 * 4];
                #pragma unroll
                for (int u = 0; u < 4; ++u) {
                    const float qa = ((const float*)&q0)[u];
                    const float qb = ((const float*)&q1)[u];
                    const float4 g0 = *(const float4*)&A_[(k4 * 4 + u) * 128 + j0];
                    const float4 g1 = *(const float4*)&A_[(k4 * 4 + u) * 128 + j1];
                    acc[0][0] += qa*g0.x; acc[0][1] += qa*g0.y; acc[0][2] += qa*g0.z; acc[0][3] += qa*g0.w;
                    acc[0][4] += qa*g1.x; acc[0][5] += qa*g1.y; acc[0][6] += qa*g1.z; acc[0][7] += qa*g1.w;
                    acc[1][0] += qb*g0.x; acc[1][1] += qb*g0.y; acc[1][2] += qb*g0.z; acc[1][3] += qb*g0.w;
                    acc[1][4] += qb*g1.x; acc[1][5] += qb*g1.y; acc[1][6] += qb*g1.z; acc[1][7] += qb*g1.w;
                }
            }

            __syncthreads();   // all G reads done (drains remaining Pt loads too)
            *(float4*)&A_[ty * 128 + j0]        = make_float4(acc[0][0], acc[0][1], acc[0][2], acc[0][3]);
            *(float4*)&A_[ty * 128 + j1]        = make_float4(acc[0][4], acc[0][5], acc[0][6], acc[0][7]);
            *(float4*)&A_[(ty + 16) * 128 + j0] = make_float4(acc[1][0], acc[1][1], acc[1][2], acc[1][3]);
            *(float4*)&A_[(ty + 16) * 128 + j1] = make_float4(acc[1][4], acc[1][5], acc[1][6], acc[1][7]);
            __syncthreads();

            // ---- phase 2: Sp rows = T @ Pt ----
            float bcc[2][8] = {};
            #pragma unroll 2
            for (int k4 = 0; k4 < 32; ++k4) {
                const float4 t0 = *(const float4*)&A_[ty * 128 + k4 * 4];
                const float4 t1 = *(const float4*)&A_[(ty + 16) * 128 + k4 * 4];
                #pragma unroll
                for (int u = 0; u < 4; ++u) {
                    const float ta = ((const float*)&t0)[u];
                    const float tb = ((const float*)&t1)[u];
                    const float4 p0 = *(const float4*)&B_[(k4 * 4 + u) * 128 + j0];
                    const float4 p1 = *(const float4*)&B_[(k4 * 4 + u) * 128 + j1];
                    bcc[0][0] += ta*p0.x; bcc[0][1] += ta*p0.y; bcc[0][2] += ta*p0.z; bcc[0][3] += ta*p0.w;
                    bcc[0][4] += ta*p1.x; bcc[0][5] += ta*p1.y; bcc[0][6] += ta*p1.z; bcc[0][7] += ta*p1.w;
                    bcc[1][0] += tb*p0.x; bcc[1][1] += tb*p0.y; bcc[1][2] += tb*p0.z; bcc[1][3] += tb*p0.w;
                    bcc[1][4] += tb*p1.x; bcc[1][5] += tb*p1.y; bcc[1][6] += tb*p1.z; bcc[1][7] += tb*p1.w;
                }
            }

            float* Sb = GS + ((size_t)(b * 8 + h)) * D * D;
            const int r0 = s * 32 + ty, r1 = r0 + 16;
            *(float4*)&Sb[r0 * D + j0] = make_float4(bcc[0][0], bcc[0][1], bcc[0][2], bcc[0][3]);
            *(float4*)&Sb[r0 * D + j1] = make_float4(bcc[0][4], bcc[0][5], bcc[0][6], bcc[0][7]);
            *(float4*)&Sb[r1 * D + j0] = make_float4(bcc[1][0], bcc[1][1], bcc[1][2], bcc[1][3]);
            *(float4*)&Sb[r1 * D + j1] = make_float4(bcc[1][4], bcc[1][5], bcc[1][6], bcc[1][7]);
        }
        __threadfence(); grid.sync(); __threadfence();   // S3

        //================ sred: S[b] = sum_h Sp[b][h] ================
        if (bid < 128) {
            const int sx = bid & 15, b = bid >> 4;
            const int idx4 = sx * 256 + t;
            float4 sum = make_float4(0.f, 0.f, 0.f, 0.f);
            #pragma unroll
            for (int h = 0; h < 8; ++h) {
                const float4 v = ((const float4*)GS)[(size_t)(b * 8 + h) * 4096 + idx4];
                sum.x += v.x; sum.y += v.y; sum.z += v.z; sum.w += v.w;
            }
            ((float4*)S)[(size_t)b * 4096 + idx4] = sum;
        }
        __threadfence(); grid.sync(); __threadfence();   // S4

        //================ z: Zout = Zin + Zin @ S ================
        {
            const int sblk = bid & 31, b = bid >> 5;
            const int ty = t >> 3, tx = t & 7;

            VMDRAIN;
            const float* Sb = S + (size_t)b * D * D;
            #pragma unroll
            for (int i = 0; i < 16; ++i)
                async16(Sb + (t + 256 * i) * 4, A_ + (t + 256 * i) * 4);

            const float* Zrow0 = Zcur + ((size_t)b * NP1 + sblk * 32) * D;
            #pragma unroll
            for (int it = 0; it < 4; ++it) {
                const int qx = t + 256 * it;
                const int r = qx >> 5, c4 = qx & 31;
                *(float4*)&C_[r * 132 + c4 * 4] = ((const float4*)(Zrow0 + r * D))[c4];
            }
            VMDRAIN;
            __syncthreads();

            float acc[16];
            #pragma unroll
            for (int q = 0; q < 16; ++q) acc[q] = 0.f;

            #pragma unroll 2
            for (int k4 = 0; k4 < 32; ++k4) {
                const float4 zq = *(const float4*)&C_[ty * 132 + k4 * 4];
                #pragma unroll
                for (int u = 0; u < 4; ++u) {
                    const float zv = ((const float*)&zq)[u];
                    #pragma unroll
                    for (int jj = 0; jj < 4; ++jj) {
                        const float4 sv = *(const float4*)&A_[(k4 * 4 + u) * 128 + 4 * tx + 32 * jj];
                        acc[jj * 4 + 0] += zv * sv.x;
                        acc[jj * 4 + 1] += zv * sv.y;
                        acc[jj * 4 + 2] += zv * sv.z;
                        acc[jj * 4 + 3] += zv * sv.w;
                    }
                }
            }

            float* Orow = out + ((size_t)b * NP1 + sblk * 32 + ty) * D;
            #pragma unroll
            for (int jj = 0; jj < 4; ++jj) {
                const int col = 4 * tx + 32 * jj;
                const float4 zr = *(const float4*)&C_[ty * 132 + col];
                float4 o;
                o.x = zr.x + acc[jj * 4 + 0];
                o.y = zr.y + acc[jj * 4 + 1];
                o.z = zr.z + acc[jj * 4 + 2];
                o.w = zr.w + acc[jj * 4 + 3];
                *(float4*)(Orow + col) = o;
            }
        }
        if (l < NL - 1) { __threadfence(); grid.sync(); __threadfence(); }   // S5
        Zcur = out;
    }
}

// ===========================================================================
// PATH B (fallback): proven round-1 multi-kernel pipeline (212 µs).
// Used only if hipLaunchCooperativeKernel returns an error.
// ===========================================================================
__global__ __launch_bounds__(256) void prep_kernel(
    const float* __restrict__ ap, float* __restrict__ Qf, float* __restrict__ Pt)
{
    const int t = threadIdx.x;
    const int base = blockIdx.x * 2048 + t * 8;
    const float inv = 1.0f / 1023.0f;
    #pragma unroll
    for (int e = 0; e < 8; ++e) {
        const int idx   = base + e;
        const int l     = idx >> 18;
        const int loc18 = idx & 262143;
        const int isP   = loc18 >> 17;
        const int local = loc18 & 131071;
        const int h = local >> 14;
        const int r = (local >> 7) & 127;
        const int c = local & 127;
        const float* apl = ap + (size_t)l * H * 2 * DM * DM;
        if (!isP) {
            float v = (r < DM && c < DM) ? apl[(h*2 + 1)*DM*DM + r*DM + c] * inv : 0.f;
            Qf[(size_t)l * H * D * D + local] = v;
        } else {
            float v;
            if (r < DM && c < DM)        v = apl[(h*2 + 0)*DM*DM + c*DM + r];
            else if (r == DM && c == DM) v = 1.f;
            else                         v = 0.f;
            Pt[(size_t)l * H * D * D + local] = v;
        }
    }
}

__global__ __launch_bounds__(256) void gp_kernel(
    const float* __restrict__ Z, float* __restrict__ Gp)
{
    const int c = blockIdx.x, q = blockIdx.y, b = blockIdx.z;
    const int t = threadIdx.x;
    __shared__ float Zs[128 * 128];
    const float* src = Z + ((size_t)b * NP1 + c * 128) * D;
    #pragma unroll
    for (int i = 0; i < 16; ++i)
        async16(src + (t + 256 * i) * 4, Zs + (t + 256 * i) * 4);
    __syncthreads();
    if (c == 7) {
        if (t < 32) ((float4*)Zs)[4064 + t] = make_float4(0.f, 0.f, 0.f, 0.f);
        __syncthreads();
    }
    const int ty = t >> 3, tx = t & 7;
    const int i0 = ty * 4, j0 = q * 32 + tx * 4;
    float acc[4][4] = {};
    #pragma unroll 4
    for (int k = 0; k < 128; ++k) {
        const float4 a  = *(const float4*)&Zs[k * 128 + i0];
        const float4 cc = *(const float4*)&Zs[k * 128 + j0];
        acc[0][0] += a.x*cc.x; acc[0][1] += a.x*cc.y; acc[0][2] += a.x*cc.z; acc[0][3] += a.x*cc.w;
        acc[1][0] += a.y*cc.x; acc[1][1] += a.y*cc.y; acc[1][2] += a.y*cc.z; acc[1][3] += a.y*cc.w;
        acc[2][0] += a.z*cc.x; acc[2][1] += a.z*cc.y; acc[2][2] += a.z*cc.z; acc[2][3] += a.z*cc.w;
        acc[3][0] += a.w*cc.x; acc[3][1] += a.w*cc.y; acc[3][2] += a.w*cc.z; acc[3][3] += a.w*cc.w;
    }
    float* Gb = Gp + ((size_t)(b * 8 + c)) * D * D;
    #pragma unroll
    for (int r = 0; r < 4; ++r)
        *(float4*)&Gb[(i0 + r) * D + j0] = make_float4(acc[r][0], acc[r][1], acc[r][2], acc[r][3]);
}

__global__ __launch_bounds__(256) void gred_kernel(
    const float* __restrict__ Gp, float* __restrict__ G)
{
    const int b = blockIdx.y;
    const int idx4 = blockIdx.x * 256 + threadIdx.x;
    float4 sum = make_float4(0.f, 0.f, 0.f, 0.f);
    #pragma unroll
    for (int c = 0; c < 8; ++c) {
        const float4 v = ((const float4*)Gp)[(size_t)(b * 8 + c) * 4096 + idx4];
        sum.x += v.x; sum.y += v.y; sum.z += v.z; sum.w += v.w;
    }
    ((float4*)G)[(size_t)b * 4096 + idx4] = sum;
}

__global__ __launch_bounds__(256) void ts_kernel(
    const float* __restrict__ Qf, const float* __restrict__ Pt,
    const float* __restrict__ G, float* __restrict__ Sp)
{
    const int s = blockIdx.x, h = blockIdx.y, b = blockIdx.z;
    const int t = threadIdx.x;
    const int ty = t >> 4, tx = t & 15;
    const int j0 = 4 * tx, j1 = 64 + 4 * tx;

    __shared__ float Qs[32 * 128];
    __shared__ float GT[128 * 128];
    __shared__ float Ps[128 * 128];

    const float* qsrc = Qf + ((size_t)h * D + s * 32) * D;
    #pragma unroll
    for (int i = 0; i < 4; ++i)  async16(qsrc + (t + 256 * i) * 4, Qs + (t + 256 * i) * 4);
    const float* gsrc = G + (size_t)b * D * D;
    #pragma unroll
    for (int i = 0; i < 16; ++i) async16(gsrc + (t + 256 * i) * 4, GT + (t + 256 * i) * 4);
    const float* psrc = Pt + (size_t)h * D * D;
    #pragma unroll
    for (int i = 0; i < 16; ++i) async16(psrc + (t + 256 * i) * 4, Ps + (t + 256 * i) * 4);

    asm volatile("s_waitcnt vmcnt(16)" ::: "memory");
    __builtin_amdgcn_s_barrier();
    asm volatile("" ::: "memory");

    float acc[2][8] = {};
    #pragma unroll 2
    for (int k4 = 0; k4 < 32; ++k4) {
        const float4 q0 = *(const float4*)&Qs[ty * 128 + k4 * 4];
        const float4 q1 = *(const float4*)&Qs[(ty + 16) * 128 + k4 * 4];
        #pragma unroll
        for (int u = 0; u < 4; ++u) {
            const float qa = ((const float*)&q0)[u];
            const float qb = ((const float*)&q1)[u];
            const float4 g0 = *(const float4*)&GT[(k4 * 4 + u) * 128 + j0];
            const float4 g1 = *(const float4*)&GT[(k4 * 4 + u) * 128 + j1];
            acc[0][0] += qa*g0.x; acc[0][1] += qa*g0.y; acc[0][2] += qa*g0.z; acc[0][3] += qa*g0.w;
            acc[0][4] += qa*g1.x; acc[0][5] += qa*g1.y; acc[0][6] += qa*g1.z; acc[0][7] += qa*g1.w;
            acc[1][0] += qb*g0.x; acc[1][1] += qb*g0.y; acc[1][2] += qb*g0.z; acc[1][3] += qb*g0.w;
            acc[1][4] += qb*g1.x; acc[1][5] += qb*g1.y; acc[1][6] += qb*g1.z; acc[1][7] += qb*g1.w;
        }
    }

    __syncthreads();
    *(float4*)&GT[ty * 128 + j0]        = make_float4(acc[0][0], acc[0][1], acc[0][2], acc[0][3]);
    *(float4*)&GT[ty * 128 + j1]        = make_float4(acc[0][4], acc[0][5], acc[0][6], acc[0][7]);
    *(float4*)&GT[(ty + 16) * 128 + j0] = make_float4(acc[1][0], acc[1][1], acc[1][2], acc[1][3]);
    *(float4*)&GT[(ty + 16) * 128 + j1] = make_float4(acc[1][4], acc[1][5], acc[1][6], acc[1][7]);
    __syncthreads();

    float bcc[2][8] = {};
    #pragma unroll 2
    for (int k4 = 0; k4 < 32; ++k4) {
        const float4 t0 = *(const float4*)&GT[ty * 128 + k4 * 4];
        const float4 t1 = *(const float4*)&GT[(ty + 16) * 128 + k4 * 4];
        #pragma unroll
        for (int u = 0; u < 4; ++u) {
            const float ta = ((const float*)&t0)[u];
            const float tb = ((const float*)&t1)[u];
            const float4 p0 = *(const float4*)&Ps[(k4 * 4 + u) * 128 + j0];
            const float4 p1 = *(const float4*)&Ps[(k4 * 4 + u) * 128 + j1];
            bcc[0][0] += ta*p0.x; bcc[0][1] += ta*p0.y; bcc[0][2] += ta*p0.z; bcc[0][3] += ta*p0.w;
            bcc[0][4] += ta*p1.x; bcc[0][5] += ta*p1.y; bcc[0][6] += ta*p1.z; bcc[0][7] += ta*p1.w;
            bcc[1][0] += tb*p0.x; bcc[1][1] += tb*p0.y; bcc[1][2] += tb*p0.z; bcc[1][3] += tb*p0.w;
            bcc[1][4] += tb*p1.x; bcc[1][5] += tb*p1.y; bcc[1][6] += tb*p1.z; bcc[1][7] += tb*p1.w;
        }
    }

    float* Sb = Sp + ((size_t)(b * 8 + h)) * D * D;
    const int r0 = s * 32 + ty, r1 = r0 + 16;
    *(float4*)&Sb[r0 * D + j0] = make_float4(bcc[0][0], bcc[0][1], bcc[0][2], bcc[0][3]);
    *(float4*)&Sb[r0 * D + j1] = make_float4(bcc[0][4], bcc[0][5], bcc[0][6], bcc[0][7]);
    *(float4*)&Sb[r1 * D + j0] = make_float4(bcc[1][0], bcc[1][1], bcc[1][2], bcc[1][3]);
    *(float4*)&Sb[r1 * D + j1] = make_float4(bcc[1][4], bcc[1][5], bcc[1][6], bcc[1][7]);
}

__global__ __launch_bounds__(256) void sred_kernel(
    const float* __restrict__ Sp, float* __restrict__ S)
{
    const int b = blockIdx.y;
    const int idx4 = blockIdx.x * 256 + threadIdx.x;
    float4 sum = make_float4(0.f, 0.f, 0.f, 0.f);
    #pragma unroll
    for (int h = 0; h < 8; ++h) {
        const float4 v = ((const float4*)Sp)[(size_t)(b * 8 + h) * 4096 + idx4];
        sum.x += v.x; sum.y += v.y; sum.z += v.z; sum.w += v.w;
    }
    ((float4*)S)[(size_t)b * 4096 + idx4] = sum;
}

__global__ __launch_bounds__(256) void z_kernel(
    const float* __restrict__ Zin, const float* __restrict__ S, float* __restrict__ Zout)
{
    const int sblk = blockIdx.x;
    const int b = blockIdx.y;
    const int t = threadIdx.x;
    const int ty = t >> 3, tx = t & 7;

    __shared__ float Zs[32 * 132];
    __shared__ float Ss[128 * 128];

    const float* Sb = S + (size_t)b * D * D;
    #pragma unroll
    for (int i = 0; i < 16; ++i)
        async16(Sb + (t + 256 * i) * 4, Ss + (t + 256 * i) * 4);

    const float* Zrow0 = Zin + ((size_t)b * NP1 + sblk * 32) * D;
    for (int q = t; q < 32 * 32; q += 256) {
        const int r = q >> 5, c4 = q & 31;
        *(float4*)&Zs[r * 132 + c4 * 4] = ((const float4*)(Zrow0 + r * D))[c4];
    }
    __syncthreads();

    float acc[16];
    #pragma unroll
    for (int q = 0; q < 16; ++q) acc[q] = 0.f;

    #pragma unroll 2
    for (int k4 = 0; k4 < 32; ++k4) {
        const float4 zq = *(const float4*)&Zs[ty * 132 + k4 * 4];
        #pragma unroll
        for (int u = 0; u < 4; ++u) {
            const float zv = ((const float*)&zq)[u];
            #pragma unroll
            for (int jj = 0; jj < 4; ++jj) {
                const float4 sv = *(const float4*)&Ss[(k4 * 4 + u) * 128 + 4 * tx + 32 * jj];
                acc[jj * 4 + 0] += zv * sv.x;
                acc[jj * 4 + 1] += zv * sv.y;
                acc[jj * 4 + 2] += zv * sv.z;
                acc[jj * 4 + 3] += zv * sv.w;
            }
        }
    }

    float* Orow = Zout + ((size_t)b * NP1 + sblk * 32 + ty) * D;
    #pragma unroll
    for (int jj = 0; jj < 4; ++jj) {
        const int col = 4 * tx + 32 * jj;
        const float4 zr = *(const float4*)&Zs[ty * 132 + col];
        float4 o;
        o.x = zr.x + acc[jj * 4 + 0];
        o.y = zr.y + acc[jj * 4 + 1];
        o.z = zr.z + acc[jj * 4 + 2];
        o.w = zr.w + acc[jj * 4 + 3];
        *(float4*)(Orow + col) = o;
    }
}

// ---------------------------------------------------------------------------
extern "C" void kernel_launch(void* const* d_in, const int* in_sizes, int n_in,
                              void* d_out, int out_size, void* d_ws, size_t ws_size,
                              hipStream_t stream)
{
    const float* Z0 = (const float*)d_in[0];
    const float* ap = (const float*)d_in[1];
    float* out = (float*)d_out;
    float* ws  = (float*)d_ws;

    float* Qf = ws + WS_QF;
    float* Pt = ws + WS_PT;
    float* G  = ws + WS_G;
    float* GS = ws + WS_GS;
    float* S  = ws + WS_S;

    void* args[] = { (void*)&Z0, (void*)&ap, (void*)&Qf, (void*)&Pt,
                     (void*)&G, (void*)&GS, (void*)&S, (void*)&out };
    hipError_t err = hipLaunchCooperativeKernel((const void*)fused_all,
                                                dim3(256), dim3(256), args, 0, stream);
    if (err != hipSuccess) {
        // Fallback: proven multi-kernel pipeline
        hipLaunchKernelGGL(prep_kernel, dim3(512), dim3(256), 0, stream, ap, Qf, Pt);
        const float* Zcur = Z0;
        for (int l = 0; l < NL; ++l) {
            const float* Qfl = Qf + (size_t)l * H * D * D;
            const float* Ptl = Pt + (size_t)l * H * D * D;
            hipLaunchKernelGGL(gp_kernel,   dim3(8, 4, B), dim3(256), 0, stream, Zcur, GS);
            hipLaunchKernelGGL(gred_kernel, dim3(16, B),   dim3(256), 0, stream, GS, G);
            hipLaunchKernelGGL(ts_kernel,   dim3(4, H, B), dim3(256), 0, stream, Qfl, Ptl, G, GS);
            hipLaunchKernelGGL(sred_kernel, dim3(16, B),   dim3(256), 0, stream, GS, S);
            hipLaunchKernelGGL(z_kernel,    dim3(32, B),   dim3(256), 0, stream, Zcur, S, out);
            Zcur = out;
        }
    }
}

// Round 5
// 286.859 us; speedup vs baseline: 5.7641x; 5.7641x over previous
//
#include <hip/hip_runtime.h>

// Problem constants
#define D    128      // d+1
#define DM   127      // d
#define NP1  1024     // N+1
#define B    8
#define H    8
#define NL   4

// Workspace layout (float offsets). Gp/Sp regions gone (atomics); keep
// generous layout for compatibility with the provided workspace size.
#define WS_QF 0                         // [NL][H][128][128] padded Q * (1/N)
#define WS_PT (WS_QF + NL*H*D*D)        // [NL][H][128][128] padded+transposed P
#define WS_G  (WS_PT + NL*H*D*D)        // [B][128][128] Gram (atomic-accumulated)
#define WS_S  (WS_G  + B*D*D)           // [B][128][128] S = sum_h (atomic-accumulated)

// Async global->LDS, 16B/lane. LDS dest = wave-uniform base + lane*16.
__device__ __forceinline__ void async16(const float* g, float* l)
{
    __builtin_amdgcn_global_load_lds(
        (const __attribute__((address_space(1))) void*)g,
        (__attribute__((address_space(3))) void*)l,
        16, 0, 0);
}

// ---------------------------------------------------------------------------
// Kernel 0 (once): pad/transpose ALL layers' params (1/N folded into Qf);
// blocks 0..127 also zero G (needed before layer-0 gp atomics).
// grid (512) x 256.
// ---------------------------------------------------------------------------
__global__ __launch_bounds__(256) void prep_kernel(
    const float* __restrict__ ap, float* __restrict__ Qf, float* __restrict__ Pt,
    float* __restrict__ G)
{
    const int t = threadIdx.x;
    const int base = blockIdx.x * 2048 + t * 8;
    const float inv = 1.0f / 1023.0f;
    #pragma unroll
    for (int e = 0; e < 8; ++e) {
        const int idx   = base + e;
        const int l     = idx >> 18;
        const int loc18 = idx & 262143;
        const int isP   = loc18 >> 17;
        const int local = loc18 & 131071;
        const int h = local >> 14;
        const int r = (local >> 7) & 127;
        const int c = local & 127;
        const float* apl = ap + (size_t)l * H * 2 * DM * DM;
        if (!isP) {
            float v = (r < DM && c < DM) ? apl[(h*2 + 1)*DM*DM + r*DM + c] * inv : 0.f;
            Qf[(size_t)l * H * D * D + local] = v;
        } else {
            float v;
            if (r < DM && c < DM)        v = apl[(h*2 + 0)*DM*DM + c*DM + r];
            else if (r == DM && c == DM) v = 1.f;
            else                         v = 0.f;
            Pt[(size_t)l * H * D * D + local] = v;
        }
    }
    // zero G: 131072 floats = 128 blocks x 256 threads x float4
    if (blockIdx.x < 128)
        ((float4*)G)[blockIdx.x * 256 + t] = make_float4(0.f, 0.f, 0.f, 0.f);
}

// ---------------------------------------------------------------------------
// Kernel 1: partial Grams, atomically accumulated into G[b].
// Also zeroes S[b] for this layer (ts's atomics come later in stream order).
// grid (8 chunks, 4 col-quarters, B) = 256 blocks.
// ---------------------------------------------------------------------------
__global__ __launch_bounds__(256) void gp_kernel(
    const float* __restrict__ Z, float* __restrict__ G, float* __restrict__ S)
{
    const int c = blockIdx.x;   // token chunk 0..7
    const int q = blockIdx.y;   // col quarter 0..3
    const int b = blockIdx.z;
    const int t = threadIdx.x;

    __shared__ float Zs[128 * 128];   // 64 KB

    const float* src = Z + ((size_t)b * NP1 + c * 128) * D;
    #pragma unroll
    for (int i = 0; i < 16; ++i)
        async16(src + (t + 256 * i) * 4, Zs + (t + 256 * i) * 4);

    // zero this block's 512-float slice of S[b] while loads are in flight
    {
        float2* Sz = (float2*)(S + (size_t)b * D * D + (c * 4 + q) * 512);
        Sz[t] = make_float2(0.f, 0.f);
    }

    __syncthreads();                  // drains vmcnt (round-1-proven)
    if (c == 7) {                     // key mask: zero token 1023 (row 127)
        if (t < 32) ((float4*)Zs)[4064 + t] = make_float4(0.f, 0.f, 0.f, 0.f);
        __syncthreads();
    }

    const int ty = t >> 3;            // 0..31 -> rows i0 = 4*ty
    const int tx = t & 7;             // 0..7  -> cols j0 = 32q + 4*tx
    const int i0 = ty * 4;
    const int j0 = q * 32 + tx * 4;

    float acc[4][4] = {};
    #pragma unroll 4
    for (int k = 0; k < 128; ++k) {
        const float4 a  = *(const float4*)&Zs[k * 128 + i0];
        const float4 cc = *(const float4*)&Zs[k * 128 + j0];
        acc[0][0] += a.x*cc.x; acc[0][1] += a.x*cc.y; acc[0][2] += a.x*cc.z; acc[0][3] += a.x*cc.w;
        acc[1][0] += a.y*cc.x; acc[1][1] += a.y*cc.y; acc[1][2] += a.y*cc.z; acc[1][3] += a.y*cc.w;
        acc[2][0] += a.z*cc.x; acc[2][1] += a.z*cc.y; acc[2][2] += a.z*cc.z; acc[2][3] += a.z*cc.w;
        acc[3][0] += a.w*cc.x; acc[3][1] += a.w*cc.y; acc[3][2] += a.w*cc.z; acc[3][3] += a.w*cc.w;
    }

    float* Gb = G + (size_t)b * D * D;
    #pragma unroll
    for (int r = 0; r < 4; ++r) {
        #pragma unroll
        for (int e = 0; e < 4; ++e)
            atomicAdd(&Gb[(i0 + r) * D + j0 + e], acc[r][e]);
    }
}

// ---------------------------------------------------------------------------
// Kernel 2: head-slice of S: (Qf_h @ G_b) @ Pt_h atomically added into S[b].
// grid (4 slices, H, B) = 256 blocks. LDS = 16 + 64 + 64 = 144 KB.
// 3 barriers; Pt arrives under phase-1 compute (vmcnt(16)). (round-1-proven)
// ---------------------------------------------------------------------------
__global__ __launch_bounds__(256) void ts_kernel(
    const float* __restrict__ Qf, const float* __restrict__ Pt,
    const float* __restrict__ G, float* __restrict__ S)
{
    const int s = blockIdx.x;   // 0..3 (row slice of 32)
    const int h = blockIdx.y;
    const int b = blockIdx.z;
    const int t = threadIdx.x;
    const int ty = t >> 4;      // 0..15 -> local rows ty, ty+16
    const int tx = t & 15;
    const int j0 = 4 * tx;
    const int j1 = 64 + 4 * tx;

    __shared__ float Qs[32 * 128];    // 16 KB
    __shared__ float GT[128 * 128];   // 64 KB: G, then reused for T (rows 0..31)
    __shared__ float Ps[128 * 128];   // 64 KB

    const float* qsrc = Qf + ((size_t)h * D + s * 32) * D;
    #pragma unroll
    for (int i = 0; i < 4; ++i)  async16(qsrc + (t + 256 * i) * 4, Qs + (t + 256 * i) * 4);
    const float* gsrc = G + (size_t)b * D * D;
    #pragma unroll
    for (int i = 0; i < 16; ++i) async16(gsrc + (t + 256 * i) * 4, GT + (t + 256 * i) * 4);
    const float* psrc = Pt + (size_t)h * D * D;
    #pragma unroll
    for (int i = 0; i < 16; ++i) async16(psrc + (t + 256 * i) * 4, Ps + (t + 256 * i) * 4);

    // wait for Q+G only (16 Pt loads may remain in flight), then barrier
    asm volatile("s_waitcnt vmcnt(16)" ::: "memory");
    __builtin_amdgcn_s_barrier();
    asm volatile("" ::: "memory");

    // ---- phase 1: T(32x128) = Qs @ G ----
    float acc[2][8] = {};
    #pragma unroll 2
    for (int k4 = 0; k4 < 32; ++k4) {
        const float4 q0 = *(const float4*)&Qs[ty * 128 + k4 * 4];
        const float4 q1 = *(const float4*)&Qs[(ty + 16) * 128 + k4 * 4];
        #pragma unroll
        for (int u = 0; u < 4; ++u) {
            const float qa = ((const float*)&q0)[u];
            const float qb = ((const float*)&q1)[u];
            const float4 g0 = *(const float4*)&GT[(k4 * 4 + u) * 128 + j0];
            const float4 g1 = *(const float4*)&GT[(k4 * 4 + u) * 128 + j1];
            acc[0][0] += qa*g0.x; acc[0][1] += qa*g0.y; acc[0][2] += qa*g0.z; acc[0][3] += qa*g0.w;
            acc[0][4] += qa*g1.x; acc[0][5] += qa*g1.y; acc[0][6] += qa*g1.z; acc[0][7] += qa*g1.w;
            acc[1][0] += qb*g0.x; acc[1][1] += qb*g0.y; acc[1][2] += qb*g0.z; acc[1][3] += qb*g0.w;
            acc[1][4] += qb*g1.x; acc[1][5] += qb*g1.y; acc[1][6] += qb*g1.z; acc[1][7] += qb*g1.w;
        }
    }

    __syncthreads();   // all G reads done (drains remaining Pt loads too)
    *(float4*)&GT[ty * 128 + j0]        = make_float4(acc[0][0], acc[0][1], acc[0][2], acc[0][3]);
    *(float4*)&GT[ty * 128 + j1]        = make_float4(acc[0][4], acc[0][5], acc[0][6], acc[0][7]);
    *(float4*)&GT[(ty + 16) * 128 + j0] = make_float4(acc[1][0], acc[1][1], acc[1][2], acc[1][3]);
    *(float4*)&GT[(ty + 16) * 128 + j1] = make_float4(acc[1][4], acc[1][5], acc[1][6], acc[1][7]);
    __syncthreads();

    // ---- phase 2: Sp rows = T @ Pt, atomically added into S ----
    float bcc[2][8] = {};
    #pragma unroll 2
    for (int k4 = 0; k4 < 32; ++k4) {
        const float4 t0 = *(const float4*)&GT[ty * 128 + k4 * 4];
        const float4 t1 = *(const float4*)&GT[(ty + 16) * 128 + k4 * 4];
        #pragma unroll
        for (int u = 0; u < 4; ++u) {
            const float ta = ((const float*)&t0)[u];
            const float tb = ((const float*)&t1)[u];
            const float4 p0 = *(const float4*)&Ps[(k4 * 4 + u) * 128 + j0];
            const float4 p1 = *(const float4*)&Ps[(k4 * 4 + u) * 128 + j1];
            bcc[0][0] += ta*p0.x; bcc[0][1] += ta*p0.y; bcc[0][2] += ta*p0.z; bcc[0][3] += ta*p0.w;
            bcc[0][4] += ta*p1.x; bcc[0][5] += ta*p1.y; bcc[0][6] += ta*p1.z; bcc[0][7] += ta*p1.w;
            bcc[1][0] += tb*p0.x; bcc[1][1] += tb*p0.y; bcc[1][2] += tb*p0.z; bcc[1][3] += tb*p0.w;
            bcc[1][4] += tb*p1.x; bcc[1][5] += tb*p1.y; bcc[1][6] += tb*p1.z; bcc[1][7] += tb*p1.w;
        }
    }

    float* Sb = S + (size_t)b * D * D;
    const int r0 = s * 32 + ty;
    const int r1 = r0 + 16;
    #pragma unroll
    for (int e = 0; e < 4; ++e) {
        atomicAdd(&Sb[r0 * D + j0 + e], bcc[0][e]);
        atomicAdd(&Sb[r0 * D + j1 + e], bcc[0][4 + e]);
        atomicAdd(&Sb[r1 * D + j0 + e], bcc[1][e]);
        atomicAdd(&Sb[r1 * D + j1 + e], bcc[1][4 + e]);
    }
}

// ---------------------------------------------------------------------------
// Kernel 3: Zout = Zin + Zin @ S. grid (32, B). Full S staged once (async),
// single barrier, uninterrupted K loop. Tail: zero G[b] for the next layer.
// ---------------------------------------------------------------------------
__global__ __launch_bounds__(256) void z_kernel(
    const float* __restrict__ Zin, const float* __restrict__ S,
    float* __restrict__ G, float* __restrict__ Zout)
{
    const int sblk = blockIdx.x;   // 0..31
    const int b = blockIdx.y;
    const int t = threadIdx.x;
    const int ty = t >> 3;         // 0..31 -> row
    const int tx = t & 7;          // cols 4tx + 32jj

    __shared__ float Zs[32 * 132]; // padded: conflict-free scalar row reads
    __shared__ float Ss[128 * 128];

    const float* Sb = S + (size_t)b * D * D;
    #pragma unroll
    for (int i = 0; i < 16; ++i)
        async16(Sb + (t + 256 * i) * 4, Ss + (t + 256 * i) * 4);

    const float* Zrow0 = Zin + ((size_t)b * NP1 + sblk * 32) * D;
    for (int q = t; q < 32 * 32; q += 256) {
        const int r = q >> 5, c4 = q & 31;
        *(float4*)&Zs[r * 132 + c4 * 4] = ((const float4*)(Zrow0 + r * D))[c4];
    }
    __syncthreads();   // drains vmcnt (S) + lgkm (Zs)

    float acc[16];
    #pragma unroll
    for (int q = 0; q < 16; ++q) acc[q] = 0.f;

    #pragma unroll 2
    for (int k4 = 0; k4 < 32; ++k4) {
        const float4 zq = *(const float4*)&Zs[ty * 132 + k4 * 4];
        #pragma unroll
        for (int u = 0; u < 4; ++u) {
            const float zv = ((const float*)&zq)[u];
            #pragma unroll
            for (int jj = 0; jj < 4; ++jj) {
                const float4 sv = *(const float4*)&Ss[(k4 * 4 + u) * 128 + 4 * tx + 32 * jj];
                acc[jj * 4 + 0] += zv * sv.x;
                acc[jj * 4 + 1] += zv * sv.y;
                acc[jj * 4 + 2] += zv * sv.z;
                acc[jj * 4 + 3] += zv * sv.w;
            }
        }
    }

    float* Orow = Zout + ((size_t)b * NP1 + sblk * 32 + ty) * D;
    #pragma unroll
    for (int jj = 0; jj < 4; ++jj) {
        const int col = 4 * tx + 32 * jj;
        const float4 zr = *(const float4*)&Zs[ty * 132 + col];
        float4 o;
        o.x = zr.x + acc[jj * 4 + 0];
        o.y = zr.y + acc[jj * 4 + 1];
        o.z = zr.z + acc[jj * 4 + 2];
        o.w = zr.w + acc[jj * 4 + 3];
        *(float4*)(Orow + col) = o;
    }

    // zero this block's 512-float slice of G[b] for next layer's gp atomics
    {
        float2* Gz = (float2*)(G + (size_t)b * D * D + sblk * 512);
        Gz[t] = make_float2(0.f, 0.f);
    }
}

// ---------------------------------------------------------------------------
extern "C" void kernel_launch(void* const* d_in, const int* in_sizes, int n_in,
                              void* d_out, int out_size, void* d_ws, size_t ws_size,
                              hipStream_t stream)
{
    const float* Z0 = (const float*)d_in[0];
    const float* ap = (const float*)d_in[1];
    float* out = (float*)d_out;
    float* ws  = (float*)d_ws;

    float* Qf = ws + WS_QF;
    float* Pt = ws + WS_PT;
    float* G  = ws + WS_G;
    float* S  = ws + WS_S;

    hipLaunchKernelGGL(prep_kernel, dim3(512), dim3(256), 0, stream, ap, Qf, Pt, G);

    const float* Zcur = Z0;
    for (int l = 0; l < NL; ++l) {
        const float* Qfl = Qf + (size_t)l * H * D * D;
        const float* Ptl = Pt + (size_t)l * H * D * D;
        hipLaunchKernelGGL(gp_kernel, dim3(8, 4, B), dim3(256), 0, stream, Zcur, G, S);
        hipLaunchKernelGGL(ts_kernel, dim3(4, H, B), dim3(256), 0, stream, Qfl, Ptl, G, S);
        hipLaunchKernelGGL(z_kernel,  dim3(32, B),   dim3(256), 0, stream, Zcur, S, G, out);
        Zcur = out;
    }
}

// Round 6
// 230.816 us; speedup vs baseline: 7.1637x; 1.2428x over previous
//
#include <hip/hip_runtime.h>

// Problem constants
#define D    128      // d+1
#define DM   127      // d
#define NP1  1024     // N+1
#define B    8
#define H    8
#define NL   4

// Workspace layout (float offsets). ~12 MB total; ws is ~268 MB (measured
// from harness poison fills), so plenty of room.
#define WS_QF 0                         // [NL][H][128][128] padded Q * (1/N)
#define WS_PT (WS_QF + NL*H*D*D)        // [NL][H][128][128] padded+transposed P
#define WS_GP (WS_PT + NL*H*D*D)        // [B][8][128][128] Gram partials
#define WS_SP (WS_GP + B*8*D*D)         // [B][8][128][128] S partials (per head)

// Async global->LDS, 16B/lane. LDS dest = wave-uniform base + lane*16.
__device__ __forceinline__ void async16(const float* g, float* l)
{
    __builtin_amdgcn_global_load_lds(
        (const __attribute__((address_space(1))) void*)g,
        (__attribute__((address_space(3))) void*)l,
        16, 0, 0);
}

// ---------------------------------------------------------------------------
// Kernel 1: partial Grams. grid (8 chunks, 4 col-quarters, B) = 256 blocks.
// Layer 0 also runs param prep (pad/transpose all layers; 1/N into Qf) while
// the Z staging loads are in flight.
// ---------------------------------------------------------------------------
__global__ __launch_bounds__(256) void gp_kernel(
    const float* __restrict__ Z, float* __restrict__ Gp,
    const float* __restrict__ ap, float* __restrict__ Qf, float* __restrict__ Pt,
    int doprep)
{
    const int c = blockIdx.x;   // token chunk 0..7
    const int q = blockIdx.y;   // col quarter 0..3
    const int b = blockIdx.z;
    const int t = threadIdx.x;

    __shared__ float Zs[128 * 128];   // 64 KB

    const float* src = Z + ((size_t)b * NP1 + c * 128) * D;
    #pragma unroll
    for (int i = 0; i < 16; ++i)
        async16(src + (t + 256 * i) * 4, Zs + (t + 256 * i) * 4);

    if (doprep) {   // uniform branch; hidden under the Z staging latency
        const int flat = blockIdx.x + 8 * blockIdx.y + 32 * blockIdx.z;  // 0..255
        const int base = flat * 4096 + t * 16;
        const float inv = 1.0f / 1023.0f;
        #pragma unroll
        for (int e = 0; e < 16; ++e) {
            const int idx   = base + e;
            const int l     = idx >> 18;
            const int loc18 = idx & 262143;
            const int isP   = loc18 >> 17;
            const int local = loc18 & 131071;
            const int h = local >> 14;
            const int r = (local >> 7) & 127;
            const int cc = local & 127;
            const float* apl = ap + (size_t)l * H * 2 * DM * DM;
            if (!isP) {
                float v = (r < DM && cc < DM) ? apl[(h*2 + 1)*DM*DM + r*DM + cc] * inv : 0.f;
                Qf[(size_t)l * H * D * D + local] = v;
            } else {
                float v;
                if (r < DM && cc < DM)       v = apl[(h*2 + 0)*DM*DM + cc*DM + r];
                else if (r == DM && cc == DM) v = 1.f;
                else                          v = 0.f;
                Pt[(size_t)l * H * D * D + local] = v;
            }
        }
    }

    __syncthreads();                  // drains vmcnt (staging complete)
    if (c == 7) {                     // key mask: zero token 1023 (row 127)
        if (t < 32) ((float4*)Zs)[4064 + t] = make_float4(0.f, 0.f, 0.f, 0.f);
        __syncthreads();
    }

    const int ty = t >> 3;            // 0..31 -> rows i0 = 4*ty
    const int tx = t & 7;             // 0..7  -> cols j0 = 32q + 4*tx
    const int i0 = ty * 4;
    const int j0 = q * 32 + tx * 4;

    float acc[4][4] = {};
    #pragma unroll 4
    for (int k = 0; k < 128; ++k) {
        const float4 a  = *(const float4*)&Zs[k * 128 + i0];
        const float4 cc = *(const float4*)&Zs[k * 128 + j0];
        acc[0][0] += a.x*cc.x; acc[0][1] += a.x*cc.y; acc[0][2] += a.x*cc.z; acc[0][3] += a.x*cc.w;
        acc[1][0] += a.y*cc.x; acc[1][1] += a.y*cc.y; acc[1][2] += a.y*cc.z; acc[1][3] += a.y*cc.w;
        acc[2][0] += a.z*cc.x; acc[2][1] += a.z*cc.y; acc[2][2] += a.z*cc.z; acc[2][3] += a.z*cc.w;
        acc[3][0] += a.w*cc.x; acc[3][1] += a.w*cc.y; acc[3][2] += a.w*cc.z; acc[3][3] += a.w*cc.w;
    }

    float* Gb = Gp + ((size_t)(b * 8 + c)) * D * D;
    #pragma unroll
    for (int r = 0; r < 4; ++r)
        *(float4*)&Gb[(i0 + r) * D + j0] =
            make_float4(acc[r][0], acc[r][1], acc[r][2], acc[r][3]);
}

// ---------------------------------------------------------------------------
// Kernel 2: Sp[b][h] = (Qf_h @ G_b) @ Pt_h with G reduced from Gp partials
// IN-KERNEL (consumer-side reduce, plain loads — no atomics).
// grid (4 slices, H, B) = 256 blocks. LDS = 16 + 64 + 64 = 144 KB.
// Load order matters for vmcnt overlap: Q async -> Gp reg loads -> Pt async
// (issued after Gp loads so consuming Gp doesn't drain Pt; Pt lands under
// phase 1).
// ---------------------------------------------------------------------------
__global__ __launch_bounds__(256) void ts_kernel(
    const float* __restrict__ Qf, const float* __restrict__ Pt,
    const float* __restrict__ Gp, float* __restrict__ Sp)
{
    const int s = blockIdx.x;   // 0..3 (row slice of 32)
    const int h = blockIdx.y;
    const int b = blockIdx.z;
    const int t = threadIdx.x;
    const int ty = t >> 4;      // 0..15 -> local rows ty, ty+16
    const int tx = t & 15;
    const int j0 = 4 * tx;
    const int j1 = 64 + 4 * tx;

    __shared__ float Qs[32 * 128];    // 16 KB
    __shared__ float GT[128 * 128];   // 64 KB: reduced G, later reused for T
    __shared__ float Ps[128 * 128];   // 64 KB

    const float* qsrc = Qf + ((size_t)h * D + s * 32) * D;
    #pragma unroll
    for (int i = 0; i < 4; ++i)  async16(qsrc + (t + 256 * i) * 4, Qs + (t + 256 * i) * 4);

    // ---- consumer-side gred: GT = sum_c Gp[b][c] (coalesced float4) ----
    const float4* Gp4 = (const float4*)(Gp + (size_t)b * 8 * D * D);
    #pragma unroll 2
    for (int i = 0; i < 16; ++i) {
        const int idx4 = t + 256 * i;
        float4 sum = Gp4[idx4];
        #pragma unroll
        for (int c = 1; c < 8; ++c) {
            const float4 v = Gp4[(size_t)c * 4096 + idx4];
            sum.x += v.x; sum.y += v.y; sum.z += v.z; sum.w += v.w;
        }
        ((float4*)GT)[idx4] = sum;
    }

    // issue Pt AFTER all Gp loads: Gp consumption above leaves these in flight
    const float* psrc = Pt + (size_t)h * D * D;
    #pragma unroll
    for (int i = 0; i < 16; ++i) async16(psrc + (t + 256 * i) * 4, Ps + (t + 256 * i) * 4);

    // barrier with LDS-drain only (Pt's 16 vm loads stay outstanding)
    asm volatile("s_waitcnt lgkmcnt(0)" ::: "memory");
    __builtin_amdgcn_s_barrier();
    asm volatile("" ::: "memory");

    // ---- phase 1: T(32x128) = Qs @ G ----
    float acc[2][8] = {};
    #pragma unroll 2
    for (int k4 = 0; k4 < 32; ++k4) {
        const float4 q0 = *(const float4*)&Qs[ty * 128 + k4 * 4];
        const float4 q1 = *(const float4*)&Qs[(ty + 16) * 128 + k4 * 4];
        #pragma unroll
        for (int u = 0; u < 4; ++u) {
            const float qa = ((const float*)&q0)[u];
            const float qb = ((const float*)&q1)[u];
            const float4 g0 = *(const float4*)&GT[(k4 * 4 + u) * 128 + j0];
            const float4 g1 = *(const float4*)&GT[(k4 * 4 + u) * 128 + j1];
            acc[0][0] += qa*g0.x; acc[0][1] += qa*g0.y; acc[0][2] += qa*g0.z; acc[0][3] += qa*g0.w;
            acc[0][4] += qa*g1.x; acc[0][5] += qa*g1.y; acc[0][6] += qa*g1.z; acc[0][7] += qa*g1.w;
            acc[1][0] += qb*g0.x; acc[1][1] += qb*g0.y; acc[1][2] += qb*g0.z; acc[1][3] += qb*g0.w;
            acc[1][4] += qb*g1.x; acc[1][5] += qb*g1.y; acc[1][6] += qb*g1.z; acc[1][7] += qb*g1.w;
        }
    }

    __syncthreads();   // all G reads done; drains remaining Pt loads (vmcnt 0)
    *(float4*)&GT[ty * 128 + j0]        = make_float4(acc[0][0], acc[0][1], acc[0][2], acc[0][3]);
    *(float4*)&GT[ty * 128 + j1]        = make_float4(acc[0][4], acc[0][5], acc[0][6], acc[0][7]);
    *(float4*)&GT[(ty + 16) * 128 + j0] = make_float4(acc[1][0], acc[1][1], acc[1][2], acc[1][3]);
    *(float4*)&GT[(ty + 16) * 128 + j1] = make_float4(acc[1][4], acc[1][5], acc[1][6], acc[1][7]);
    __syncthreads();

    // ---- phase 2: Sp rows = T @ Pt ----
    float bcc[2][8] = {};
    #pragma unroll 2
    for (int k4 = 0; k4 < 32; ++k4) {
        const float4 t0 = *(const float4*)&GT[ty * 128 + k4 * 4];
        const float4 t1 = *(const float4*)&GT[(ty + 16) * 128 + k4 * 4];
        #pragma unroll
        for (int u = 0; u < 4; ++u) {
            const float ta = ((const float*)&t0)[u];
            const float tb = ((const float*)&t1)[u];
            const float4 p0 = *(const float4*)&Ps[(k4 * 4 + u) * 128 + j0];
            const float4 p1 = *(const float4*)&Ps[(k4 * 4 + u) * 128 + j1];
            bcc[0][0] += ta*p0.x; bcc[0][1] += ta*p0.y; bcc[0][2] += ta*p0.z; bcc[0][3] += ta*p0.w;
            bcc[0][4] += ta*p1.x; bcc[0][5] += ta*p1.y; bcc[0][6] += ta*p1.z; bcc[0][7] += ta*p1.w;
            bcc[1][0] += tb*p0.x; bcc[1][1] += tb*p0.y; bcc[1][2] += tb*p0.z; bcc[1][3] += tb*p0.w;
            bcc[1][4] += tb*p1.x; bcc[1][5] += tb*p1.y; bcc[1][6] += tb*p1.z; bcc[1][7] += tb*p1.w;
        }
    }

    float* Sb = Sp + ((size_t)(b * 8 + h)) * D * D;
    const int r0 = s * 32 + ty;
    const int r1 = r0 + 16;
    *(float4*)&Sb[r0 * D + j0] = make_float4(bcc[0][0], bcc[0][1], bcc[0][2], bcc[0][3]);
    *(float4*)&Sb[r0 * D + j1] = make_float4(bcc[0][4], bcc[0][5], bcc[0][6], bcc[0][7]);
    *(float4*)&Sb[r1 * D + j0] = make_float4(bcc[1][0], bcc[1][1], bcc[1][2], bcc[1][3]);
    *(float4*)&Sb[r1 * D + j1] = make_float4(bcc[1][4], bcc[1][5], bcc[1][6], bcc[1][7]);
}

// ---------------------------------------------------------------------------
// Kernel 3: Zout = Zin + Zin @ S with S reduced from Sp partials IN-KERNEL
// (consumer-side reduce; 1/N already folded into Qf). grid (32, B).
// ---------------------------------------------------------------------------
__global__ __launch_bounds__(256) void z_kernel(
    const float* __restrict__ Zin, const float* __restrict__ Sp,
    float* __restrict__ Zout)
{
    const int sblk = blockIdx.x;   // 0..31
    const int b = blockIdx.y;
    const int t = threadIdx.x;
    const int ty = t >> 3;         // 0..31 -> row
    const int tx = t & 7;          // cols 4tx + 32jj

    __shared__ float Zs[32 * 132]; // padded: conflict-free scalar row reads
    __shared__ float Ss[128 * 128];

    // ---- consumer-side sred: Ss = sum_h Sp[b][h] (coalesced float4) ----
    const float4* Sp4 = (const float4*)(Sp + (size_t)b * 8 * D * D);
    #pragma unroll 2
    for (int i = 0; i < 16; ++i) {
        const int idx4 = t + 256 * i;
        float4 sum = Sp4[idx4];
        #pragma unroll
        for (int h = 1; h < 8; ++h) {
            const float4 v = Sp4[(size_t)h * 4096 + idx4];
            sum.x += v.x; sum.y += v.y; sum.z += v.z; sum.w += v.w;
        }
        ((float4*)Ss)[idx4] = sum;
    }

    const float* Zrow0 = Zin + ((size_t)b * NP1 + sblk * 32) * D;
    #pragma unroll
    for (int it = 0; it < 4; ++it) {
        const int qx = t + 256 * it;
        const int r = qx >> 5, c4 = qx & 31;
        *(float4*)&Zs[r * 132 + c4 * 4] = ((const float4*)(Zrow0 + r * D))[c4];
    }
    __syncthreads();

    float acc[16];
    #pragma unroll
    for (int q = 0; q < 16; ++q) acc[q] = 0.f;

    #pragma unroll 2
    for (int k4 = 0; k4 < 32; ++k4) {
        const float4 zq = *(const float4*)&Zs[ty * 132 + k4 * 4];
        #pragma unroll
        for (int u = 0; u < 4; ++u) {
            const float zv = ((const float*)&zq)[u];
            #pragma unroll
            for (int jj = 0; jj < 4; ++jj) {
                const float4 sv = *(const float4*)&Ss[(k4 * 4 + u) * 128 + 4 * tx + 32 * jj];
                acc[jj * 4 + 0] += zv * sv.x;
                acc[jj * 4 + 1] += zv * sv.y;
                acc[jj * 4 + 2] += zv * sv.z;
                acc[jj * 4 + 3] += zv * sv.w;
            }
        }
    }

    float* Orow = Zout + ((size_t)b * NP1 + sblk * 32 + ty) * D;
    #pragma unroll
    for (int jj = 0; jj < 4; ++jj) {
        const int col = 4 * tx + 32 * jj;
        const float4 zr = *(const float4*)&Zs[ty * 132 + col];
        float4 o;
        o.x = zr.x + acc[jj * 4 + 0];
        o.y = zr.y + acc[jj * 4 + 1];
        o.z = zr.z + acc[jj * 4 + 2];
        o.w = zr.w + acc[jj * 4 + 3];
        *(float4*)(Orow + col) = o;
    }
}

// ---------------------------------------------------------------------------
extern "C" void kernel_launch(void* const* d_in, const int* in_sizes, int n_in,
                              void* d_out, int out_size, void* d_ws, size_t ws_size,
                              hipStream_t stream)
{
    const float* Z0 = (const float*)d_in[0];
    const float* ap = (const float*)d_in[1];
    float* out = (float*)d_out;
    float* ws  = (float*)d_ws;

    float* Qf = ws + WS_QF;
    float* Pt = ws + WS_PT;
    float* Gp = ws + WS_GP;
    float* Sp = ws + WS_SP;

    const float* Zcur = Z0;
    for (int l = 0; l < NL; ++l) {
        const float* Qfl = Qf + (size_t)l * H * D * D;
        const float* Ptl = Pt + (size_t)l * H * D * D;
        hipLaunchKernelGGL(gp_kernel, dim3(8, 4, B), dim3(256), 0, stream,
                           Zcur, Gp, ap, Qf, Pt, (l == 0) ? 1 : 0);
        hipLaunchKernelGGL(ts_kernel, dim3(4, H, B), dim3(256), 0, stream, Qfl, Ptl, Gp, Sp);
        hipLaunchKernelGGL(z_kernel,  dim3(32, B),   dim3(256), 0, stream, Zcur, Sp, out);
        Zcur = out;
    }
}

// Round 7
// 209.845 us; speedup vs baseline: 7.8796x; 1.0999x over previous
//
#include <hip/hip_runtime.h>

// Problem constants
#define D    128      // d+1
#define DM   127      // d
#define NP1  1024     // N+1
#define B    8
#define H    8
#define NL   4

// Workspace layout (float offsets)
#define WS_QF 0                         // [NL][H][128][128] padded Q * (1/N)
#define WS_PT (WS_QF + NL*H*D*D)        // [NL][H][128][128] padded+transposed P
#define WS_G  (WS_PT + NL*H*D*D)        // [B][128][128] reduced Gram
#define WS_GS (WS_G  + B*D*D)           // [B][8][128][128] shared: Gp partials, then Sp partials
#define WS_S  (WS_GS + B*8*D*D)         // [B][128][128] S = sum_h Sp

// Async global->LDS, 16B/lane. LDS dest = wave-uniform base + lane*16
// (t-linear indexing keeps each wave's 64 lanes contiguous).
__device__ __forceinline__ void async16(const float* g, float* l)
{
    __builtin_amdgcn_global_load_lds(
        (const __attribute__((address_space(1))) void*)g,
        (__attribute__((address_space(3))) void*)l,
        16, 0, 0);
}

// ---------------------------------------------------------------------------
// Kernel 1: partial Grams. grid (8 chunks, 4 col-quarters, B) = 256 blocks
// x 512 threads (8 waves/CU = 2/SIMD). Layer 0 also runs param prep while
// the Z staging loads are in flight.
// ---------------------------------------------------------------------------
__global__ __launch_bounds__(512) void gp_kernel(
    const float* __restrict__ Z, float* __restrict__ Gp,
    const float* __restrict__ ap, float* __restrict__ Qf, float* __restrict__ Pt,
    int doprep)
{
    const int c = blockIdx.x;   // token chunk 0..7
    const int q = blockIdx.y;   // col quarter 0..3
    const int b = blockIdx.z;
    const int t = threadIdx.x;

    __shared__ float Zs[128 * 128];   // 64 KB

    const float* src = Z + ((size_t)b * NP1 + c * 128) * D;
    #pragma unroll
    for (int i = 0; i < 8; ++i)
        async16(src + (t + 512 * i) * 4, Zs + (t + 512 * i) * 4);

    if (doprep) {   // uniform branch; hidden under the Z staging latency
        const int flat = blockIdx.x + 8 * blockIdx.y + 32 * blockIdx.z;  // 0..255
        const int base = flat * 4096 + t * 8;
        const float inv = 1.0f / 1023.0f;
        #pragma unroll
        for (int e = 0; e < 8; ++e) {
            const int idx   = base + e;
            const int l     = idx >> 18;
            const int loc18 = idx & 262143;
            const int isP   = loc18 >> 17;
            const int local = loc18 & 131071;
            const int h = local >> 14;
            const int r = (local >> 7) & 127;
            const int cc = local & 127;
            const float* apl = ap + (size_t)l * H * 2 * DM * DM;
            if (!isP) {
                float v = (r < DM && cc < DM) ? apl[(h*2 + 1)*DM*DM + r*DM + cc] * inv : 0.f;
                Qf[(size_t)l * H * D * D + local] = v;
            } else {
                float v;
                if (r < DM && cc < DM)        v = apl[(h*2 + 0)*DM*DM + cc*DM + r];
                else if (r == DM && cc == DM) v = 1.f;
                else                          v = 0.f;
                Pt[(size_t)l * H * D * D + local] = v;
            }
        }
    }

    __syncthreads();                  // drains vmcnt (staging complete)
    if (c == 7) {                     // key mask: zero token 1023 (row 127)
        if (t < 32) ((float4*)Zs)[4064 + t] = make_float4(0.f, 0.f, 0.f, 0.f);
        __syncthreads();
    }

    const int ty = t >> 3;            // 0..63 -> rows i0 = 2*ty
    const int tx = t & 7;             // 0..7  -> cols j0 = 32q + 4*tx
    const int i0 = ty * 2;
    const int j0 = q * 32 + tx * 4;

    float acc[2][4] = {};
    #pragma unroll 4
    for (int k = 0; k < 128; ++k) {
        const float2 a  = *(const float2*)&Zs[k * 128 + i0];
        const float4 cc = *(const float4*)&Zs[k * 128 + j0];
        acc[0][0] += a.x*cc.x; acc[0][1] += a.x*cc.y; acc[0][2] += a.x*cc.z; acc[0][3] += a.x*cc.w;
        acc[1][0] += a.y*cc.x; acc[1][1] += a.y*cc.y; acc[1][2] += a.y*cc.z; acc[1][3] += a.y*cc.w;
    }

    float* Gb = Gp + ((size_t)(b * 8 + c)) * D * D;
    *(float4*)&Gb[(i0 + 0) * D + j0] = make_float4(acc[0][0], acc[0][1], acc[0][2], acc[0][3]);
    *(float4*)&Gb[(i0 + 1) * D + j0] = make_float4(acc[1][0], acc[1][1], acc[1][2], acc[1][3]);
}

// ---------------------------------------------------------------------------
// Kernel 2: G[b] = sum_c Gp[b][c]. grid (16, B) = 128 blocks x 256.
// ---------------------------------------------------------------------------
__global__ __launch_bounds__(256) void gred_kernel(
    const float* __restrict__ Gp, float* __restrict__ G)
{
    const int b = blockIdx.y;
    const int idx4 = blockIdx.x * 256 + threadIdx.x;
    float4 sum = make_float4(0.f, 0.f, 0.f, 0.f);
    #pragma unroll
    for (int c = 0; c < 8; ++c) {
        const float4 v = ((const float4*)Gp)[(size_t)(b * 8 + c) * 4096 + idx4];
        sum.x += v.x; sum.y += v.y; sum.z += v.z; sum.w += v.w;
    }
    ((float4*)G)[(size_t)b * 4096 + idx4] = sum;
}

// ---------------------------------------------------------------------------
// Kernel 3: Sp[b][h] = (Qf_h @ G_b) @ Pt_h, fused, fully LDS-staged.
// grid (4 slices, H, B) = 256 blocks x 512 threads. LDS = 144 KB.
// 3 barriers; Pt arrives under phase-1 compute (vmcnt(8) gate).
// ---------------------------------------------------------------------------
__global__ __launch_bounds__(512) void ts_kernel(
    const float* __restrict__ Qf, const float* __restrict__ Pt,
    const float* __restrict__ G, float* __restrict__ Sp)
{
    const int s = blockIdx.x;   // 0..3 (row slice of 32)
    const int h = blockIdx.y;
    const int b = blockIdx.z;
    const int t = threadIdx.x;
    const int ty = t >> 4;      // 0..31 -> local row
    const int tx = t & 15;
    const int j0 = 4 * tx;
    const int j1 = 64 + 4 * tx;

    __shared__ float Qs[32 * 128];    // 16 KB
    __shared__ float GT[128 * 128];   // 64 KB: G, then reused for T (rows 0..31)
    __shared__ float Ps[128 * 128];   // 64 KB

    const float* qsrc = Qf + ((size_t)h * D + s * 32) * D;
    #pragma unroll
    for (int i = 0; i < 2; ++i)  async16(qsrc + (t + 512 * i) * 4, Qs + (t + 512 * i) * 4);
    const float* gsrc = G + (size_t)b * D * D;
    #pragma unroll
    for (int i = 0; i < 8; ++i)  async16(gsrc + (t + 512 * i) * 4, GT + (t + 512 * i) * 4);
    const float* psrc = Pt + (size_t)h * D * D;
    #pragma unroll
    for (int i = 0; i < 8; ++i)  async16(psrc + (t + 512 * i) * 4, Ps + (t + 512 * i) * 4);

    // wait for Q+G only (8 Pt loads may remain in flight), then barrier
    asm volatile("s_waitcnt vmcnt(8)" ::: "memory");
    __builtin_amdgcn_s_barrier();
    asm volatile("" ::: "memory");

    // ---- phase 1: T(32x128) = Qs @ G ----
    float acc[8] = {};
    #pragma unroll 2
    for (int k4 = 0; k4 < 32; ++k4) {
        const float4 q0 = *(const float4*)&Qs[ty * 128 + k4 * 4];
        #pragma unroll
        for (int u = 0; u < 4; ++u) {
            const float qa = ((const float*)&q0)[u];
            const float4 g0 = *(const float4*)&GT[(k4 * 4 + u) * 128 + j0];
            const float4 g1 = *(const float4*)&GT[(k4 * 4 + u) * 128 + j1];
            acc[0] += qa*g0.x; acc[1] += qa*g0.y; acc[2] += qa*g0.z; acc[3] += qa*g0.w;
            acc[4] += qa*g1.x; acc[5] += qa*g1.y; acc[6] += qa*g1.z; acc[7] += qa*g1.w;
        }
    }

    __syncthreads();   // all G reads done (also drains remaining Pt loads)
    *(float4*)&GT[ty * 128 + j0] = make_float4(acc[0], acc[1], acc[2], acc[3]);
    *(float4*)&GT[ty * 128 + j1] = make_float4(acc[4], acc[5], acc[6], acc[7]);
    __syncthreads();

    // ---- phase 2: Sp rows = T @ Pt ----
    float bcc[8] = {};
    #pragma unroll 2
    for (int k4 = 0; k4 < 32; ++k4) {
        const float4 t0 = *(const float4*)&GT[ty * 128 + k4 * 4];
        #pragma unroll
        for (int u = 0; u < 4; ++u) {
            const float ta = ((const float*)&t0)[u];
            const float4 p0 = *(const float4*)&Ps[(k4 * 4 + u) * 128 + j0];
            const float4 p1 = *(const float4*)&Ps[(k4 * 4 + u) * 128 + j1];
            bcc[0] += ta*p0.x; bcc[1] += ta*p0.y; bcc[2] += ta*p0.z; bcc[3] += ta*p0.w;
            bcc[4] += ta*p1.x; bcc[5] += ta*p1.y; bcc[6] += ta*p1.z; bcc[7] += ta*p1.w;
        }
    }

    float* Sb = Sp + ((size_t)(b * 8 + h)) * D * D;
    const int r0 = s * 32 + ty;
    *(float4*)&Sb[r0 * D + j0] = make_float4(bcc[0], bcc[1], bcc[2], bcc[3]);
    *(float4*)&Sb[r0 * D + j1] = make_float4(bcc[4], bcc[5], bcc[6], bcc[7]);
}

// ---------------------------------------------------------------------------
// Kernel 4: S[b] = sum_h Sp[b][h]. grid (16, B) = 128 blocks x 256.
// ---------------------------------------------------------------------------
__global__ __launch_bounds__(256) void sred_kernel(
    const float* __restrict__ Sp, float* __restrict__ S)
{
    const int b = blockIdx.y;
    const int idx4 = blockIdx.x * 256 + threadIdx.x;
    float4 sum = make_float4(0.f, 0.f, 0.f, 0.f);
    #pragma unroll
    for (int h = 0; h < 8; ++h) {
        const float4 v = ((const float4*)Sp)[(size_t)(b * 8 + h) * 4096 + idx4];
        sum.x += v.x; sum.y += v.y; sum.z += v.z; sum.w += v.w;
    }
    ((float4*)S)[(size_t)b * 4096 + idx4] = sum;
}

// ---------------------------------------------------------------------------
// Kernel 5: Zout = Zin + Zin @ S. grid (32, B) = 256 blocks x 512 threads.
// Full S staged once (async), single barrier, uninterrupted K loop.
// ---------------------------------------------------------------------------
__global__ __launch_bounds__(512) void z_kernel(
    const float* __restrict__ Zin, const float* __restrict__ S, float* __restrict__ Zout)
{
    const int sblk = blockIdx.x;   // 0..31
    const int b = blockIdx.y;
    const int t = threadIdx.x;
    const int ty = t >> 4;         // 0..31 -> row
    const int tx = t & 15;         // cols 4tx + 64jj, jj=0..1

    __shared__ float Zs[32 * 132]; // padded: conflict-free scalar row reads
    __shared__ float Ss[128 * 128];

    const float* Sb = S + (size_t)b * D * D;
    #pragma unroll
    for (int i = 0; i < 8; ++i)
        async16(Sb + (t + 512 * i) * 4, Ss + (t + 512 * i) * 4);

    const float* Zrow0 = Zin + ((size_t)b * NP1 + sblk * 32) * D;
    #pragma unroll
    for (int it = 0; it < 2; ++it) {
        const int qx = t + 512 * it;
        const int r = qx >> 5, c4 = qx & 31;
        *(float4*)&Zs[r * 132 + c4 * 4] = ((const float4*)(Zrow0 + r * D))[c4];
    }
    __syncthreads();   // drains vmcnt (S) + lgkm (Zs)

    float acc[8];
    #pragma unroll
    for (int qq = 0; qq < 8; ++qq) acc[qq] = 0.f;

    #pragma unroll 2
    for (int k4 = 0; k4 < 32; ++k4) {
        const float4 zq = *(const float4*)&Zs[ty * 132 + k4 * 4];
        #pragma unroll
        for (int u = 0; u < 4; ++u) {
            const float zv = ((const float*)&zq)[u];
            #pragma unroll
            for (int jj = 0; jj < 2; ++jj) {
                const float4 sv = *(const float4*)&Ss[(k4 * 4 + u) * 128 + 4 * tx + 64 * jj];
                acc[jj * 4 + 0] += zv * sv.x;
                acc[jj * 4 + 1] += zv * sv.y;
                acc[jj * 4 + 2] += zv * sv.z;
                acc[jj * 4 + 3] += zv * sv.w;
            }
        }
    }

    float* Orow = Zout + ((size_t)b * NP1 + sblk * 32 + ty) * D;
    #pragma unroll
    for (int jj = 0; jj < 2; ++jj) {
        const int col = 4 * tx + 64 * jj;
        const float4 zr = *(const float4*)&Zs[ty * 132 + col];
        float4 o;
        o.x = zr.x + acc[jj * 4 + 0];
        o.y = zr.y + acc[jj * 4 + 1];
        o.z = zr.z + acc[jj * 4 + 2];
        o.w = zr.w + acc[jj * 4 + 3];
        *(float4*)(Orow + col) = o;
    }
}

// ---------------------------------------------------------------------------
extern "C" void kernel_launch(void* const* d_in, const int* in_sizes, int n_in,
                              void* d_out, int out_size, void* d_ws, size_t ws_size,
                              hipStream_t stream)
{
    const float* Z0 = (const float*)d_in[0];
    const float* ap = (const float*)d_in[1];
    float* out = (float*)d_out;
    float* ws  = (float*)d_ws;

    float* Qf = ws + WS_QF;
    float* Pt = ws + WS_PT;
    float* G  = ws + WS_G;
    float* GS = ws + WS_GS;   // Gp then Sp (disjoint lifetimes within a layer)
    float* S  = ws + WS_S;

    const float* Zcur = Z0;
    for (int l = 0; l < NL; ++l) {
        const float* Qfl = Qf + (size_t)l * H * D * D;
        const float* Ptl = Pt + (size_t)l * H * D * D;
        hipLaunchKernelGGL(gp_kernel,   dim3(8, 4, B), dim3(512), 0, stream,
                           Zcur, GS, ap, Qf, Pt, (l == 0) ? 1 : 0);
        hipLaunchKernelGGL(gred_kernel, dim3(16, B),   dim3(256), 0, stream, GS, G);
        hipLaunchKernelGGL(ts_kernel,   dim3(4, H, B), dim3(512), 0, stream, Qfl, Ptl, G, GS);
        hipLaunchKernelGGL(sred_kernel, dim3(16, B),   dim3(256), 0, stream, GS, S);
        hipLaunchKernelGGL(z_kernel,    dim3(32, B),   dim3(512), 0, stream, Zcur, S, out);
        Zcur = out;
    }
}

// Round 9
// 165.570 us; speedup vs baseline: 9.9867x; 1.2674x over previous
//
#include <hip/hip_runtime.h>

// Problem constants
#define D    128      // d+1
#define DM   127      // d
#define NP1  1024     // N+1
#define B    8
#define H    8
#define NL   4

typedef __attribute__((ext_vector_type(8))) __bf16 bf16x8;
typedef __attribute__((ext_vector_type(8))) unsigned short ushort8;
typedef __attribute__((ext_vector_type(4))) float f32x4;

// Workspace layout (float offsets). ~11 MB total.
#define WS_GP  0                        // [B][8][128][128] f32 Gram partials (symmetric)
#define WS_SPT (WS_GP + B*8*D*D)        // [B][H][128][128] f32 Sp TRANSPOSED (Spt[c][r])
#define WS_QB  (WS_SPT + B*H*D*D)       // [NL][H][128][128] bf16 Q*(1/N), swizzled
#define WS_PB  (WS_QB + NL*H*D*D/2)     // [NL][H][128][128] bf16 P padded (+corner 1), swizzled
#define WS_GB  (WS_PB + NL*H*D*D/2)     // [B][128][128] bf16 G, swizzled
#define WS_ST  (WS_GB + B*D*D/2)        // [B][128][128] bf16 S^T (St[n][k]), swizzled

// Async global->LDS, 16B/lane (dest = wave-uniform base + lane*16; linear).
__device__ __forceinline__ void async16(const void* g, void* l)
{
    __builtin_amdgcn_global_load_lds(
        (const __attribute__((address_space(1))) void*)g,
        (__attribute__((address_space(3))) void*)l,
        16, 0, 0);
}

// fp32 -> bf16 with round-to-nearest-even
__device__ __forceinline__ unsigned short f2bf(float f)
{
    unsigned int u = __float_as_uint(f);
    u += 0x7fffu + ((u >> 16) & 1u);
    return (unsigned short)(u >> 16);
}

// Swizzled elem index for bf16 [*][128] row-major tiles: col ^= (row&7)<<3.
// XOR touches bits 3-5 only -> commutes with +j (j<8) at 8-aligned bases.
__device__ __forceinline__ int SW(int row, int col)
{
    return row * 128 + (col ^ ((row & 7) << 3));
}

// A/B fragment load from a swizzled bf16 LDS tile ([rows][128]).
// lane l supplies matrix row (row0 + (l&15)), k = k0 + (l>>4)*8 + j.
// Any consistent k-enumeration cancels between A and B frags.
__device__ __forceinline__ bf16x8 fragAB(const unsigned short* Lb, int row0, int k0, int lane)
{
    const int r = row0 + (lane & 15);
    const int c = (k0 + ((lane >> 4) << 3)) ^ ((r & 7) << 3);
    union { ushort8 u; bf16x8 b; } U;
    U.u = *(const ushort8*)&Lb[r * 128 + c];
    return U.b;
}

#define MFMA(a, b, c) __builtin_amdgcn_mfma_f32_16x16x32_bf16((a), (b), (c), 0, 0, 0)

// ---------------------------------------------------------------------------
// prep (once): Qb = pad(Q)*(1/N), Pb = pad(P) with corner 1 — bf16, swizzled.
// grid 128 x 256 (FIX: index space is [NL][2][H][128][64 pairs] = 2^19, so
// 128 blocks x 256 thr x 16 items — round 8's 256 blocks read OOB on ap).
// ---------------------------------------------------------------------------
__global__ __launch_bounds__(256) void prep_kernel(
    const float* __restrict__ ap, unsigned short* __restrict__ Qb,
    unsigned short* __restrict__ Pb)
{
    const int t = threadIdx.x;
    const float inv = 1.0f / 1023.0f;
    #pragma unroll
    for (int e = 0; e < 16; ++e) {
        const int p  = blockIdx.x * 4096 + e * 256 + t;   // 0 .. 2^19-1
        const int c  = (p & 63) * 2;
        const int r  = (p >> 6) & 127;
        const int h  = (p >> 13) & 7;
        const int isP = (p >> 16) & 1;
        const int l  = (p >> 17) & 3;
        const float* apl = ap + ((size_t)(l * H + h) * 2 + (isP ? 0 : 1)) * DM * DM;
        float v0, v1;
        if (!isP) {
            v0 = (r < DM && c     < DM) ? apl[r * DM + c] * inv     : 0.f;
            v1 = (r < DM && c + 1 < DM) ? apl[r * DM + c + 1] * inv : 0.f;
        } else {
            v0 = (r < DM && c     < DM) ? apl[r * DM + c]     : 0.f;
            v1 = (r < DM && c + 1 < DM) ? apl[r * DM + c + 1]
                 : ((r == DM && c + 1 == DM) ? 1.f : 0.f);
        }
        unsigned short* base = (isP ? Pb : Qb) + (size_t)(l * H + h) * D * D;
        const int el = SW(r, c);
        ((unsigned int*)base)[el >> 1] =
            (unsigned int)f2bf(v0) | ((unsigned int)f2bf(v1) << 16);
    }
}

// ---------------------------------------------------------------------------
// gp: per (chunk c, b): full 128x128 Gram (over dims, token-summed) via MFMA.
// grid (8, B) = 64 blocks x 256 thr. Stage Z fp32 -> transpose-convert to
// bf16 Zt[dim][token] (swizzled) -> 64 MFMA tiles. Output stored transposed
// (valid: chunk Gram symmetric).
// ---------------------------------------------------------------------------
__global__ __launch_bounds__(256) void gp_kernel(
    const float* __restrict__ Z, float* __restrict__ Gp)
{
    const int c = blockIdx.x, b = blockIdx.y;
    const int t = threadIdx.x, lane = t & 63, w = t >> 6;

    __shared__ __align__(16) float Zs[128 * 128];          // 64 KB fp32 staging
    __shared__ __align__(16) unsigned short Zt[128 * 128]; // 32 KB bf16 transposed swizzled

    const float* src = Z + ((size_t)b * NP1 + c * 128) * D;
    #pragma unroll
    for (int i = 0; i < 16; ++i)
        async16(src + (t + 256 * i) * 4, Zs + (t + 256 * i) * 4);
    __syncthreads();   // drains vmcnt

    // transpose-convert: Zt[d][tok] = bf16(Zs[tok][d]); diagonal tk to spread banks
    {
        const int d = t >> 1, half = t & 1;
        const int sft = (d & 7) << 3;
        #pragma unroll 4
        for (int tp = 0; tp < 32; ++tp) {
            const int tk = ((tp + d) & 31) * 2 + half * 64;
            float v0 = Zs[tk * 128 + d];
            float v1 = Zs[(tk + 1) * 128 + d];
            if (c == 7 && tk == 126) v1 = 0.f;   // key mask: token 1023
            ((unsigned int*)Zt)[(d * 128 + (tk ^ sft)) >> 1] =
                (unsigned int)f2bf(v0) | ((unsigned int)f2bf(v1) << 16);
        }
    }
    __syncthreads();

    // MFMA: wave w covers m-tiles {2w, 2w+1} x all 8 n-tiles, K=128
    f32x4 acc[2][8] = {};
    #pragma unroll
    for (int k0 = 0; k0 < 128; k0 += 32) {
        const bf16x8 a0 = fragAB(Zt, (w * 2 + 0) * 16, k0, lane);
        const bf16x8 a1 = fragAB(Zt, (w * 2 + 1) * 16, k0, lane);
        #pragma unroll
        for (int nt = 0; nt < 8; ++nt) {
            const bf16x8 bb = fragAB(Zt, nt * 16, k0, lane);
            acc[0][nt] = MFMA(a0, bb, acc[0][nt]);
            acc[1][nt] = MFMA(a1, bb, acc[1][nt]);
        }
    }

    float* Gb = Gp + ((size_t)(b * 8 + c)) * D * D;
    #pragma unroll
    for (int m = 0; m < 2; ++m) {
        const int rg = (w * 2 + m) * 16 + ((lane >> 4) << 2);
        #pragma unroll
        for (int nt = 0; nt < 8; ++nt) {
            const int cg = nt * 16 + (lane & 15);
            *(f32x4*)&Gb[cg * 128 + rg] = acc[m][nt];   // transposed store (symmetric)
        }
    }
}

// ---------------------------------------------------------------------------
// gred: G[b] = sum_c Gp[b][c] -> bf16 swizzled. grid (16, B) x 256.
// ---------------------------------------------------------------------------
__global__ __launch_bounds__(256) void gred_kernel(
    const float* __restrict__ Gp, unsigned short* __restrict__ Gbf)
{
    const int b = blockIdx.y;
    const int idx4 = blockIdx.x * 256 + threadIdx.x;   // 0..4095
    float4 sum = make_float4(0.f, 0.f, 0.f, 0.f);
    #pragma unroll
    for (int c = 0; c < 8; ++c) {
        const float4 v = ((const float4*)Gp)[(size_t)(b * 8 + c) * 4096 + idx4];
        sum.x += v.x; sum.y += v.y; sum.z += v.z; sum.w += v.w;
    }
    const int row = idx4 >> 5;
    const int n0  = (idx4 & 31) * 4;
    const int el  = SW(row, n0);
    unsigned int* dst = (unsigned int*)(Gbf + (size_t)b * D * D);
    dst[(el >> 1) + 0] = (unsigned int)f2bf(sum.x) | ((unsigned int)f2bf(sum.y) << 16);
    dst[(el >> 1) + 1] = (unsigned int)f2bf(sum.z) | ((unsigned int)f2bf(sum.w) << 16);
}

// ---------------------------------------------------------------------------
// ts: T = Qf_h @ G_b (MFMA), Spt = (T @ P_h^T)^T (MFMA, transposed f32x4 store).
// grid (4 slices, H, B) = 256 blocks x 256 thr. LDS = 8+32+32+8 = 80 KB.
// ---------------------------------------------------------------------------
__global__ __launch_bounds__(256) void ts_kernel(
    const unsigned short* __restrict__ Qb, const unsigned short* __restrict__ Pb,
    const unsigned short* __restrict__ Gbf, float* __restrict__ Spt)
{
    const int s = blockIdx.x, h = blockIdx.y, b = blockIdx.z;
    const int t = threadIdx.x, lane = t & 63, w = t >> 6;

    __shared__ __align__(16) unsigned short Qs[32 * 128];   // 8 KB
    __shared__ __align__(16) unsigned short Gs[128 * 128];  // 32 KB
    __shared__ __align__(16) unsigned short Ps[128 * 128];  // 32 KB
    __shared__ __align__(16) unsigned short Tb[32 * 128];   // 8 KB

    const unsigned short* qsrc = Qb + (size_t)h * D * D + s * 32 * 128;
    #pragma unroll
    for (int i = 0; i < 2; ++i)
        async16((const char*)qsrc + (t + 256 * i) * 16, (char*)Qs + (t + 256 * i) * 16);
    const unsigned short* gsrc = Gbf + (size_t)b * D * D;
    #pragma unroll
    for (int i = 0; i < 8; ++i)
        async16((const char*)gsrc + (t + 256 * i) * 16, (char*)Gs + (t + 256 * i) * 16);
    const unsigned short* psrc = Pb + (size_t)h * D * D;
    #pragma unroll
    for (int i = 0; i < 8; ++i)
        async16((const char*)psrc + (t + 256 * i) * 16, (char*)Ps + (t + 256 * i) * 16);

    // wait for Q+G (10 oldest of 18); Ps's 8 stay in flight under phase 1
    asm volatile("s_waitcnt vmcnt(8)" ::: "memory");
    __builtin_amdgcn_s_barrier();
    asm volatile("" ::: "memory");

    // phase 1: T(32x128) = Qs @ G (G symmetric). wave w: n-tiles {2w, 2w+1}
    f32x4 accT[2][2] = {};
    #pragma unroll
    for (int k0 = 0; k0 < 128; k0 += 32) {
        const bf16x8 a0 = fragAB(Qs, 0, k0, lane);
        const bf16x8 a1 = fragAB(Qs, 16, k0, lane);
        const bf16x8 b0 = fragAB(Gs, (w * 2 + 0) * 16, k0, lane);
        const bf16x8 b1 = fragAB(Gs, (w * 2 + 1) * 16, k0, lane);
        accT[0][0] = MFMA(a0, b0, accT[0][0]);
        accT[0][1] = MFMA(a0, b1, accT[0][1]);
        accT[1][0] = MFMA(a1, b0, accT[1][0]);
        accT[1][1] = MFMA(a1, b1, accT[1][1]);
    }
    // write T to LDS bf16 swizzled (D-frag: row=(lane>>4)*4+j, col=lane&15)
    #pragma unroll
    for (int m = 0; m < 2; ++m) {
        #pragma unroll
        for (int nl = 0; nl < 2; ++nl) {
            const int cc = (w * 2 + nl) * 16 + (lane & 15);
            const int r0 = m * 16 + ((lane >> 4) << 2);
            #pragma unroll
            for (int j = 0; j < 4; ++j)
                Tb[SW(r0 + j, cc)] = f2bf(accT[m][nl][j]);
        }
    }
    __syncthreads();   // T visible; also drains Ps loads (vmcnt 0)

    // phase 2: Sp(32x128) = T @ P^T; B-frag = rows of (untransposed) P
    f32x4 accS[2][2] = {};
    #pragma unroll
    for (int k0 = 0; k0 < 128; k0 += 32) {
        const bf16x8 a0 = fragAB(Tb, 0, k0, lane);
        const bf16x8 a1 = fragAB(Tb, 16, k0, lane);
        const bf16x8 b0 = fragAB(Ps, (w * 2 + 0) * 16, k0, lane);
        const bf16x8 b1 = fragAB(Ps, (w * 2 + 1) * 16, k0, lane);
        accS[0][0] = MFMA(a0, b0, accS[0][0]);
        accS[0][1] = MFMA(a0, b1, accS[0][1]);
        accS[1][0] = MFMA(a1, b0, accS[1][0]);
        accS[1][1] = MFMA(a1, b1, accS[1][1]);
    }

    // store TRANSPOSED (Spt[c][r]) so the D-frag's 4 rows become one f32x4
    float* SptBH = Spt + (size_t)(b * 8 + h) * D * D;
    #pragma unroll
    for (int m = 0; m < 2; ++m) {
        const int rg = s * 32 + m * 16 + ((lane >> 4) << 2);
        #pragma unroll
        for (int nl = 0; nl < 2; ++nl) {
            const int cg = (w * 2 + nl) * 16 + (lane & 15);
            *(f32x4*)&SptBH[cg * 128 + rg] = accS[m][nl];
        }
    }
}

// ---------------------------------------------------------------------------
// sred: St[n][k] = bf16( sum_h Spt[b][h][n][k] ), swizzled. grid (16, B) x 256.
// (St[n][k] = S[k][n] since Spt holds the head-transposed S contribution.)
// ---------------------------------------------------------------------------
__global__ __launch_bounds__(256) void sred_kernel(
    const float* __restrict__ Spt, unsigned short* __restrict__ St)
{
    const int b = blockIdx.y;
    const int idx4 = blockIdx.x * 256 + threadIdx.x;
    float4 sum = make_float4(0.f, 0.f, 0.f, 0.f);
    #pragma unroll
    for (int h = 0; h < 8; ++h) {
        const float4 v = ((const float4*)Spt)[(size_t)(b * 8 + h) * 4096 + idx4];
        sum.x += v.x; sum.y += v.y; sum.z += v.z; sum.w += v.w;
    }
    const int row = idx4 >> 5;
    const int k0  = (idx4 & 31) * 4;
    const int el  = SW(row, k0);
    unsigned int* dst = (unsigned int*)(St + (size_t)b * D * D);
    dst[(el >> 1) + 0] = (unsigned int)f2bf(sum.x) | ((unsigned int)f2bf(sum.y) << 16);
    dst[(el >> 1) + 1] = (unsigned int)f2bf(sum.z) | ((unsigned int)f2bf(sum.w) << 16);
}

// ---------------------------------------------------------------------------
// z: out = Z + Z @ S via MFMA (A = bf16(Z rows), B = St rows). grid (32, B).
// Residual add in fp32 from the staged Zs. LDS = 16+8+32 = 56 KB.
// In-place safe: each block reads only its own 32 rows of Zin.
// ---------------------------------------------------------------------------
__global__ __launch_bounds__(256) void z_kernel(
    const float* __restrict__ Zin, const unsigned short* __restrict__ St,
    float* __restrict__ Zout)
{
    const int sblk = blockIdx.x, b = blockIdx.y;
    const int t = threadIdx.x, lane = t & 63, w = t >> 6;

    __shared__ __align__(16) float Zs[32 * 128];            // 16 KB fp32 staging
    __shared__ __align__(16) unsigned short Zb[32 * 128];   // 8 KB bf16 swizzled
    __shared__ __align__(16) unsigned short Ss[128 * 128];  // 32 KB bf16 swizzled (S^T)

    const float* zsrc = Zin + ((size_t)b * NP1 + sblk * 32) * D;
    #pragma unroll
    for (int i = 0; i < 4; ++i)
        async16(zsrc + (t + 256 * i) * 4, Zs + (t + 256 * i) * 4);
    const unsigned short* ssrc = St + (size_t)b * D * D;
    #pragma unroll
    for (int i = 0; i < 8; ++i)
        async16((const char*)ssrc + (t + 256 * i) * 16, (char*)Ss + (t + 256 * i) * 16);

    // Zs (oldest 4) done; Ss may still be in flight
    asm volatile("s_waitcnt vmcnt(8)" ::: "memory");
    __builtin_amdgcn_s_barrier();
    asm volatile("" ::: "memory");

    // convert Z rows to bf16 swizzled
    {
        const int r = t >> 3, c0 = (t & 7) * 16;
        const int sft = (r & 7) << 3;
        #pragma unroll
        for (int cc = 0; cc < 16; cc += 2) {
            const float v0 = Zs[r * 128 + c0 + cc];
            const float v1 = Zs[r * 128 + c0 + cc + 1];
            ((unsigned int*)Zb)[(r * 128 + ((c0 + cc) ^ sft)) >> 1] =
                (unsigned int)f2bf(v0) | ((unsigned int)f2bf(v1) << 16);
        }
    }
    __syncthreads();   // Zb visible; drains Ss loads

    // res(32x128) = Zb @ S; wave w: n-tiles {2w,2w+1}, m-tiles {0,1}
    f32x4 accR[2][2] = {};
    #pragma unroll
    for (int k0 = 0; k0 < 128; k0 += 32) {
        const bf16x8 a0 = fragAB(Zb, 0, k0, lane);
        const bf16x8 a1 = fragAB(Zb, 16, k0, lane);
        const bf16x8 b0 = fragAB(Ss, (w * 2 + 0) * 16, k0, lane);
        const bf16x8 b1 = fragAB(Ss, (w * 2 + 1) * 16, k0, lane);
        accR[0][0] = MFMA(a0, b0, accR[0][0]);
        accR[0][1] = MFMA(a0, b1, accR[0][1]);
        accR[1][0] = MFMA(a1, b0, accR[1][0]);
        accR[1][1] = MFMA(a1, b1, accR[1][1]);
    }

    // epilogue: out = Zs(fp32) + res
    #pragma unroll
    for (int m = 0; m < 2; ++m) {
        const int r0 = m * 16 + ((lane >> 4) << 2);
        #pragma unroll
        for (int nl = 0; nl < 2; ++nl) {
            const int cc = (w * 2 + nl) * 16 + (lane & 15);
            #pragma unroll
            for (int j = 0; j < 4; ++j) {
                const int r = r0 + j;
                Zout[((size_t)b * NP1 + sblk * 32 + r) * D + cc] =
                    Zs[r * 128 + cc] + accR[m][nl][j];
            }
        }
    }
}

// ---------------------------------------------------------------------------
extern "C" void kernel_launch(void* const* d_in, const int* in_sizes, int n_in,
                              void* d_out, int out_size, void* d_ws, size_t ws_size,
                              hipStream_t stream)
{
    const float* Z0 = (const float*)d_in[0];
    const float* ap = (const float*)d_in[1];
    float* out = (float*)d_out;
    float* ws  = (float*)d_ws;

    float* Gp  = ws + WS_GP;
    float* Spt = ws + WS_SPT;
    unsigned short* Qb  = (unsigned short*)(ws + WS_QB);
    unsigned short* Pb  = (unsigned short*)(ws + WS_PB);
    unsigned short* Gbf = (unsigned short*)(ws + WS_GB);
    unsigned short* St  = (unsigned short*)(ws + WS_ST);

    hipLaunchKernelGGL(prep_kernel, dim3(128), dim3(256), 0, stream, ap, Qb, Pb);

    const float* Zcur = Z0;
    for (int l = 0; l < NL; ++l) {
        const unsigned short* Qbl = Qb + (size_t)l * H * D * D;
        const unsigned short* Pbl = Pb + (size_t)l * H * D * D;
        hipLaunchKernelGGL(gp_kernel,   dim3(8, B),    dim3(256), 0, stream, Zcur, Gp);
        hipLaunchKernelGGL(gred_kernel, dim3(16, B),   dim3(256), 0, stream, Gp, Gbf);
        hipLaunchKernelGGL(ts_kernel,   dim3(4, H, B), dim3(256), 0, stream, Qbl, Pbl, Gbf, Spt);
        hipLaunchKernelGGL(sred_kernel, dim3(16, B),   dim3(256), 0, stream, Spt, St);
        hipLaunchKernelGGL(z_kernel,    dim3(32, B),   dim3(256), 0, stream, Zcur, St, out);
        Zcur = out;
    }
}

// Round 10
// 147.163 us; speedup vs baseline: 11.2357x; 1.1251x over previous
//
#include <hip/hip_runtime.h>

// Problem constants
#define D    128      // d+1
#define DM   127      // d
#define NP1  1024     // N+1
#define B    8
#define H    8
#define NL   4

typedef __attribute__((ext_vector_type(8))) __bf16 bf16x8;
typedef __attribute__((ext_vector_type(8))) unsigned short ushort8;
typedef __attribute__((ext_vector_type(4))) unsigned short ushort4v;
typedef __attribute__((ext_vector_type(4))) float f32x4;

// Workspace layout (float offsets). ~14.5 MB total.
#define WS_GP  0                        // [B][8][128][128] f32 Gram partials (symmetric)
#define WS_SPT (WS_GP + B*8*D*D)        // [B][H][128][128] f32 Sp TRANSPOSED
#define WS_QB  (WS_SPT + B*H*D*D)       // [NL][H][128][128] bf16 Q*(1/N), swizzled
#define WS_PB  (WS_QB + NL*H*D*D/2)     // [NL][H][128][128] bf16 P padded (+corner 1), swizzled
#define WS_GB  (WS_PB + NL*H*D*D/2)     // [B][128][128] bf16 G, swizzled
#define WS_ST  (WS_GB + B*D*D/2)        // [B][128][128] bf16 S^T, swizzled
#define WS_ZT  (WS_ST + B*D*D/2)        // [B][8][128][128] bf16 Z^T per chunk, swizzled, tok1023-masked

// Async global->LDS, 16B/lane (dest = wave-uniform base + lane*16; linear).
__device__ __forceinline__ void async16(const void* g, void* l)
{
    __builtin_amdgcn_global_load_lds(
        (const __attribute__((address_space(1))) void*)g,
        (__attribute__((address_space(3))) void*)l,
        16, 0, 0);
}

// fp32 -> bf16 round-to-nearest-even
__device__ __forceinline__ unsigned short f2bf(float f)
{
    unsigned int u = __float_as_uint(f);
    u += 0x7fffu + ((u >> 16) & 1u);
    return (unsigned short)(u >> 16);
}

// Swizzled elem index for bf16 [*][128] row-major tiles: col ^= (row&7)<<3.
__device__ __forceinline__ int SW(int row, int col)
{
    return row * 128 + (col ^ ((row & 7) << 3));
}

// A/B fragment from a swizzled bf16 LDS tile: lane supplies matrix row
// row0+(l&15), k = k0 + (l>>4)*8 + j. k-enumeration cancels between A and B.
__device__ __forceinline__ bf16x8 fragAB(const unsigned short* Lb, int row0, int k0, int lane)
{
    const int r = row0 + (lane & 15);
    const int c = (k0 + ((lane >> 4) << 3)) ^ ((r & 7) << 3);
    union { ushort8 u; bf16x8 b; } U;
    U.u = *(const ushort8*)&Lb[r * 128 + c];
    return U.b;
}

#define MFMA(a, b, c) __builtin_amdgcn_mfma_f32_16x16x32_bf16((a), (b), (c), 0, 0, 0)

// ---------------------------------------------------------------------------
// prep (once): Qb = pad(Q)*(1/N), Pb = pad(P)+corner1 — bf16 swizzled.
// grid 128 x 256; index space [NL][2][H][128][64 pairs] = 2^19. (round-9 proven)
// ---------------------------------------------------------------------------
__global__ __launch_bounds__(256) void prep_kernel(
    const float* __restrict__ ap, unsigned short* __restrict__ Qb,
    unsigned short* __restrict__ Pb)
{
    const int t = threadIdx.x;
    const float inv = 1.0f / 1023.0f;
    #pragma unroll
    for (int e = 0; e < 16; ++e) {
        const int p  = blockIdx.x * 4096 + e * 256 + t;
        const int c  = (p & 63) * 2;
        const int r  = (p >> 6) & 127;
        const int h  = (p >> 13) & 7;
        const int isP = (p >> 16) & 1;
        const int l  = (p >> 17) & 3;
        const float* apl = ap + ((size_t)(l * H + h) * 2 + (isP ? 0 : 1)) * DM * DM;
        float v0, v1;
        if (!isP) {
            v0 = (r < DM && c     < DM) ? apl[r * DM + c] * inv     : 0.f;
            v1 = (r < DM && c + 1 < DM) ? apl[r * DM + c + 1] * inv : 0.f;
        } else {
            v0 = (r < DM && c     < DM) ? apl[r * DM + c]     : 0.f;
            v1 = (r < DM && c + 1 < DM) ? apl[r * DM + c + 1]
                 : ((r == DM && c + 1 == DM) ? 1.f : 0.f);
        }
        unsigned short* base = (isP ? Pb : Qb) + (size_t)(l * H + h) * D * D;
        const int el = SW(r, c);
        ((unsigned int*)base)[el >> 1] =
            (unsigned int)f2bf(v0) | ((unsigned int)f2bf(v1) << 16);
    }
}

// ---------------------------------------------------------------------------
// ztr0 (once): Ztr[b][c][d][tok] = bf16(Z0[b][c*128+tok][d]), swizzled,
// token 1023 zeroed. grid (8, B) x 256. Coalesced final store via LDS.
// ---------------------------------------------------------------------------
__global__ __launch_bounds__(256) void ztr0_kernel(
    const float* __restrict__ Z, unsigned short* __restrict__ Ztr)
{
    const int c = blockIdx.x, b = blockIdx.y;
    const int t = threadIdx.x;

    __shared__ __align__(16) float Zs[128 * 128];          // 64 KB
    __shared__ __align__(16) unsigned short Zt[128 * 128]; // 32 KB

    const float* src = Z + ((size_t)b * NP1 + c * 128) * D;
    #pragma unroll
    for (int i = 0; i < 16; ++i)
        async16(src + (t + 256 * i) * 4, Zs + (t + 256 * i) * 4);
    __syncthreads();

    {
        const int d = t >> 1, half = t & 1;
        const int sft = (d & 7) << 3;
        #pragma unroll 4
        for (int tp = 0; tp < 32; ++tp) {
            const int tk = ((tp + d) & 31) * 2 + half * 64;
            float v0 = Zs[tk * 128 + d];
            float v1 = Zs[(tk + 1) * 128 + d];
            if (c == 7 && tk == 126) v1 = 0.f;   // key mask: token 1023
            ((unsigned int*)Zt)[(d * 128 + (tk ^ sft)) >> 1] =
                (unsigned int)f2bf(v0) | ((unsigned int)f2bf(v1) << 16);
        }
    }
    __syncthreads();

    ushort8* dst = (ushort8*)(Ztr + (size_t)(b * 8 + c) * D * D);
    #pragma unroll
    for (int i = 0; i < 8; ++i)
        dst[t + 256 * i] = ((const ushort8*)Zt)[t + 256 * i];
}

// ---------------------------------------------------------------------------
// gp: Gram partial of chunk c via MFMA, directly from bf16 Ztr (no fp32
// stage, no convert). grid (8 chunks, 4 n-quarters, B) = 256 blocks x 256.
// Wave w: m-tiles {2w,2w+1} (all 128 rows over 4 waves) x block's 2 n-tiles.
// Output stored transposed (chunk Gram symmetric). LDS = 32 KB.
// ---------------------------------------------------------------------------
__global__ __launch_bounds__(256) void gp_kernel(
    const unsigned short* __restrict__ Ztr, float* __restrict__ Gp)
{
    const int c = blockIdx.x, q = blockIdx.y, b = blockIdx.z;
    const int t = threadIdx.x, lane = t & 63, w = t >> 6;

    __shared__ __align__(16) unsigned short Zt[128 * 128]; // 32 KB

    const unsigned short* src = Ztr + (size_t)(b * 8 + c) * D * D;
    #pragma unroll
    for (int i = 0; i < 8; ++i)
        async16((const char*)src + (t + 256 * i) * 16, (char*)Zt + (t + 256 * i) * 16);
    __syncthreads();

    f32x4 acc[2][2] = {};
    #pragma unroll
    for (int k0 = 0; k0 < 128; k0 += 32) {
        const bf16x8 a0 = fragAB(Zt, (w * 2 + 0) * 16, k0, lane);
        const bf16x8 a1 = fragAB(Zt, (w * 2 + 1) * 16, k0, lane);
        const bf16x8 b0 = fragAB(Zt, q * 32,      k0, lane);
        const bf16x8 b1 = fragAB(Zt, q * 32 + 16, k0, lane);
        acc[0][0] = MFMA(a0, b0, acc[0][0]);
        acc[0][1] = MFMA(a0, b1, acc[0][1]);
        acc[1][0] = MFMA(a1, b0, acc[1][0]);
        acc[1][1] = MFMA(a1, b1, acc[1][1]);
    }

    float* Gb = Gp + ((size_t)(b * 8 + c)) * D * D;
    #pragma unroll
    for (int m = 0; m < 2; ++m) {
        const int rg = (w * 2 + m) * 16 + ((lane >> 4) << 2);
        #pragma unroll
        for (int nl = 0; nl < 2; ++nl) {
            const int cg = q * 32 + nl * 16 + (lane & 15);
            *(f32x4*)&Gb[cg * 128 + rg] = acc[m][nl];   // transposed store (symmetric)
        }
    }
}

// ---------------------------------------------------------------------------
// gred: G[b] = sum_c Gp[b][c] -> bf16 swizzled. grid (16, B) x 256. (proven)
// ---------------------------------------------------------------------------
__global__ __launch_bounds__(256) void gred_kernel(
    const float* __restrict__ Gp, unsigned short* __restrict__ Gbf)
{
    const int b = blockIdx.y;
    const int idx4 = blockIdx.x * 256 + threadIdx.x;   // 0..4095
    float4 sum = make_float4(0.f, 0.f, 0.f, 0.f);
    #pragma unroll
    for (int c = 0; c < 8; ++c) {
        const float4 v = ((const float4*)Gp)[(size_t)(b * 8 + c) * 4096 + idx4];
        sum.x += v.x; sum.y += v.y; sum.z += v.z; sum.w += v.w;
    }
    const int row = idx4 >> 5;
    const int n0  = (idx4 & 31) * 4;
    const int el  = SW(row, n0);
    unsigned int* dst = (unsigned int*)(Gbf + (size_t)b * D * D);
    dst[(el >> 1) + 0] = (unsigned int)f2bf(sum.x) | ((unsigned int)f2bf(sum.y) << 16);
    dst[(el >> 1) + 1] = (unsigned int)f2bf(sum.z) | ((unsigned int)f2bf(sum.w) << 16);
}

// ---------------------------------------------------------------------------
// ts: T = Qf_h @ G_b; Spt = (T @ P_h^T)^T. grid (4, H, B) x 256. (proven)
// ---------------------------------------------------------------------------
__global__ __launch_bounds__(256) void ts_kernel(
    const unsigned short* __restrict__ Qb, const unsigned short* __restrict__ Pb,
    const unsigned short* __restrict__ Gbf, float* __restrict__ Spt)
{
    const int s = blockIdx.x, h = blockIdx.y, b = blockIdx.z;
    const int t = threadIdx.x, lane = t & 63, w = t >> 6;

    __shared__ __align__(16) unsigned short Qs[32 * 128];   // 8 KB
    __shared__ __align__(16) unsigned short Gs[128 * 128];  // 32 KB
    __shared__ __align__(16) unsigned short Ps[128 * 128];  // 32 KB
    __shared__ __align__(16) unsigned short Tb[32 * 128];   // 8 KB

    const unsigned short* qsrc = Qb + (size_t)h * D * D + s * 32 * 128;
    #pragma unroll
    for (int i = 0; i < 2; ++i)
        async16((const char*)qsrc + (t + 256 * i) * 16, (char*)Qs + (t + 256 * i) * 16);
    const unsigned short* gsrc = Gbf + (size_t)b * D * D;
    #pragma unroll
    for (int i = 0; i < 8; ++i)
        async16((const char*)gsrc + (t + 256 * i) * 16, (char*)Gs + (t + 256 * i) * 16);
    const unsigned short* psrc = Pb + (size_t)h * D * D;
    #pragma unroll
    for (int i = 0; i < 8; ++i)
        async16((const char*)psrc + (t + 256 * i) * 16, (char*)Ps + (t + 256 * i) * 16);

    // wait for Q+G; Ps's 8 loads stay in flight under phase 1
    asm volatile("s_waitcnt vmcnt(8)" ::: "memory");
    __builtin_amdgcn_s_barrier();
    asm volatile("" ::: "memory");

    f32x4 accT[2][2] = {};
    #pragma unroll
    for (int k0 = 0; k0 < 128; k0 += 32) {
        const bf16x8 a0 = fragAB(Qs, 0, k0, lane);
        const bf16x8 a1 = fragAB(Qs, 16, k0, lane);
        const bf16x8 b0 = fragAB(Gs, (w * 2 + 0) * 16, k0, lane);
        const bf16x8 b1 = fragAB(Gs, (w * 2 + 1) * 16, k0, lane);
        accT[0][0] = MFMA(a0, b0, accT[0][0]);
        accT[0][1] = MFMA(a0, b1, accT[0][1]);
        accT[1][0] = MFMA(a1, b0, accT[1][0]);
        accT[1][1] = MFMA(a1, b1, accT[1][1]);
    }
    #pragma unroll
    for (int m = 0; m < 2; ++m) {
        #pragma unroll
        for (int nl = 0; nl < 2; ++nl) {
            const int cc = (w * 2 + nl) * 16 + (lane & 15);
            const int r0 = m * 16 + ((lane >> 4) << 2);
            #pragma unroll
            for (int j = 0; j < 4; ++j)
                Tb[SW(r0 + j, cc)] = f2bf(accT[m][nl][j]);
        }
    }
    __syncthreads();   // T visible; drains Ps loads

    f32x4 accS[2][2] = {};
    #pragma unroll
    for (int k0 = 0; k0 < 128; k0 += 32) {
        const bf16x8 a0 = fragAB(Tb, 0, k0, lane);
        const bf16x8 a1 = fragAB(Tb, 16, k0, lane);
        const bf16x8 b0 = fragAB(Ps, (w * 2 + 0) * 16, k0, lane);
        const bf16x8 b1 = fragAB(Ps, (w * 2 + 1) * 16, k0, lane);
        accS[0][0] = MFMA(a0, b0, accS[0][0]);
        accS[0][1] = MFMA(a0, b1, accS[0][1]);
        accS[1][0] = MFMA(a1, b0, accS[1][0]);
        accS[1][1] = MFMA(a1, b1, accS[1][1]);
    }

    float* SptBH = Spt + (size_t)(b * 8 + h) * D * D;
    #pragma unroll
    for (int m = 0; m < 2; ++m) {
        const int rg = s * 32 + m * 16 + ((lane >> 4) << 2);
        #pragma unroll
        for (int nl = 0; nl < 2; ++nl) {
            const int cg = (w * 2 + nl) * 16 + (lane & 15);
            *(f32x4*)&SptBH[cg * 128 + rg] = accS[m][nl];
        }
    }
}

// ---------------------------------------------------------------------------
// sred: St = bf16( sum_h Spt[b][h] ), swizzled. grid (16, B) x 256. (proven)
// ---------------------------------------------------------------------------
__global__ __launch_bounds__(256) void sred_kernel(
    const float* __restrict__ Spt, unsigned short* __restrict__ St)
{
    const int b = blockIdx.y;
    const int idx4 = blockIdx.x * 256 + threadIdx.x;
    float4 sum = make_float4(0.f, 0.f, 0.f, 0.f);
    #pragma unroll
    for (int h = 0; h < 8; ++h) {
        const float4 v = ((const float4*)Spt)[(size_t)(b * 8 + h) * 4096 + idx4];
        sum.x += v.x; sum.y += v.y; sum.z += v.z; sum.w += v.w;
    }
    const int row = idx4 >> 5;
    const int k0  = (idx4 & 31) * 4;
    const int el  = SW(row, k0);
    unsigned int* dst = (unsigned int*)(St + (size_t)b * D * D);
    dst[(el >> 1) + 0] = (unsigned int)f2bf(sum.x) | ((unsigned int)f2bf(sum.y) << 16);
    dst[(el >> 1) + 1] = (unsigned int)f2bf(sum.z) | ((unsigned int)f2bf(sum.w) << 16);
}

// ---------------------------------------------------------------------------
// z: out = Z + Z @ S via MFMA; also emits next layer's Ztr (bf16 transposed
// swizzled, token-1023-masked) straight from the epilogue registers.
// grid (32, B) x 256. LDS = 56 KB.
// ---------------------------------------------------------------------------
__global__ __launch_bounds__(256) void z_kernel(
    const float* __restrict__ Zin, const unsigned short* __restrict__ St,
    float* __restrict__ Zout, unsigned short* __restrict__ Ztr, int writeZtr)
{
    const int sblk = blockIdx.x, b = blockIdx.y;
    const int t = threadIdx.x, lane = t & 63, w = t >> 6;

    __shared__ __align__(16) float Zs[32 * 128];            // 16 KB fp32 staging
    __shared__ __align__(16) unsigned short Zb[32 * 128];   // 8 KB bf16 swizzled
    __shared__ __align__(16) unsigned short Ss[128 * 128];  // 32 KB bf16 swizzled (S^T)

    const float* zsrc = Zin + ((size_t)b * NP1 + sblk * 32) * D;
    #pragma unroll
    for (int i = 0; i < 4; ++i)
        async16(zsrc + (t + 256 * i) * 4, Zs + (t + 256 * i) * 4);
    const unsigned short* ssrc = St + (size_t)b * D * D;
    #pragma unroll
    for (int i = 0; i < 8; ++i)
        async16((const char*)ssrc + (t + 256 * i) * 16, (char*)Ss + (t + 256 * i) * 16);

    asm volatile("s_waitcnt vmcnt(8)" ::: "memory");
    __builtin_amdgcn_s_barrier();
    asm volatile("" ::: "memory");

    {
        const int r = t >> 3, c0 = (t & 7) * 16;
        const int sft = (r & 7) << 3;
        #pragma unroll
        for (int cc = 0; cc < 16; cc += 2) {
            const float v0 = Zs[r * 128 + c0 + cc];
            const float v1 = Zs[r * 128 + c0 + cc + 1];
            ((unsigned int*)Zb)[(r * 128 + ((c0 + cc) ^ sft)) >> 1] =
                (unsigned int)f2bf(v0) | ((unsigned int)f2bf(v1) << 16);
        }
    }
    __syncthreads();   // Zb visible; drains Ss loads

    f32x4 accR[2][2] = {};
    #pragma unroll
    for (int k0 = 0; k0 < 128; k0 += 32) {
        const bf16x8 a0 = fragAB(Zb, 0, k0, lane);
        const bf16x8 a1 = fragAB(Zb, 16, k0, lane);
        const bf16x8 b0 = fragAB(Ss, (w * 2 + 0) * 16, k0, lane);
        const bf16x8 b1 = fragAB(Ss, (w * 2 + 1) * 16, k0, lane);
        accR[0][0] = MFMA(a0, b0, accR[0][0]);
        accR[0][1] = MFMA(a0, b1, accR[0][1]);
        accR[1][0] = MFMA(a1, b0, accR[1][0]);
        accR[1][1] = MFMA(a1, b1, accR[1][1]);
    }

    // epilogue: out = Zs + res; optional transposed bf16 emit for next gp
    #pragma unroll
    for (int m = 0; m < 2; ++m) {
        const int r0 = m * 16 + ((lane >> 4) << 2);
        #pragma unroll
        for (int nl = 0; nl < 2; ++nl) {
            const int cc = (w * 2 + nl) * 16 + (lane & 15);
            float o[4];
            #pragma unroll
            for (int j = 0; j < 4; ++j) {
                const int r = r0 + j;
                o[j] = Zs[r * 128 + cc] + accR[m][nl][j];
                Zout[((size_t)b * NP1 + sblk * 32 + r) * D + cc] = o[j];
            }
            if (writeZtr) {
                const int gt0   = sblk * 32 + r0;       // global token of j=0
                const int chunk = gt0 >> 7;
                const int tok0  = gt0 & 127;            // 4-aligned -> 8B run contiguous under SW
                ushort4v v;
                #pragma unroll
                for (int j = 0; j < 4; ++j)
                    v[j] = (gt0 + j == 1023) ? (unsigned short)0 : f2bf(o[j]);
                unsigned short* tile = Ztr + (size_t)(b * 8 + chunk) * D * D;
                *(ushort4v*)&tile[SW(cc, tok0)] = v;
            }
        }
    }
}

// ---------------------------------------------------------------------------
extern "C" void kernel_launch(void* const* d_in, const int* in_sizes, int n_in,
                              void* d_out, int out_size, void* d_ws, size_t ws_size,
                              hipStream_t stream)
{
    const float* Z0 = (const float*)d_in[0];
    const float* ap = (const float*)d_in[1];
    float* out = (float*)d_out;
    float* ws  = (float*)d_ws;

    float* Gp  = ws + WS_GP;
    float* Spt = ws + WS_SPT;
    unsigned short* Qb  = (unsigned short*)(ws + WS_QB);
    unsigned short* Pb  = (unsigned short*)(ws + WS_PB);
    unsigned short* Gbf = (unsigned short*)(ws + WS_GB);
    unsigned short* St  = (unsigned short*)(ws + WS_ST);
    unsigned short* Ztr = (unsigned short*)(ws + WS_ZT);

    hipLaunchKernelGGL(prep_kernel, dim3(128),  dim3(256), 0, stream, ap, Qb, Pb);
    hipLaunchKernelGGL(ztr0_kernel, dim3(8, B), dim3(256), 0, stream, Z0, Ztr);

    const float* Zcur = Z0;
    for (int l = 0; l < NL; ++l) {
        const unsigned short* Qbl = Qb + (size_t)l * H * D * D;
        const unsigned short* Pbl = Pb + (size_t)l * H * D * D;
        hipLaunchKernelGGL(gp_kernel,   dim3(8, 4, B), dim3(256), 0, stream, Ztr, Gp);
        hipLaunchKernelGGL(gred_kernel, dim3(16, B),   dim3(256), 0, stream, Gp, Gbf);
        hipLaunchKernelGGL(ts_kernel,   dim3(4, H, B), dim3(256), 0, stream, Qbl, Pbl, Gbf, Spt);
        hipLaunchKernelGGL(sred_kernel, dim3(16, B),   dim3(256), 0, stream, Spt, St);
        hipLaunchKernelGGL(z_kernel,    dim3(32, B),   dim3(256), 0, stream,
                           Zcur, St, out, Ztr, (l < NL - 1) ? 1 : 0);
        Zcur = out;
    }
}